// Round 5
// baseline (388.627 us; speedup 1.0000x reference)
//
#include <hip/hip_runtime.h>
#include <stdint.h>

#define N_ 2
#define C_ 256
#define SP 512
#define H1 128
#define H2 64
#define H3 32

using f32x4 = __attribute__((ext_vector_type(4))) float;
using s16x8 = __attribute__((ext_vector_type(8))) short;

__device__ __forceinline__ uint32_t f2bf_rne(float x) {
    uint32_t u = __builtin_bit_cast(uint32_t, x);
    return (u + 0x7FFFu + ((u >> 16) & 1u)) >> 16;
}
__device__ __forceinline__ float bf2f(uint32_t h) {
    return __builtin_bit_cast(float, h << 16);
}

// A[n*SP+i][k] = sum_c points[n][c][i] * W0[c][k] + 0.5*b0[k]
// 4 independent partial sums break the serial fma chain (ILP).
__global__ __launch_bounds__(512) void k_precompA(
    const float* __restrict__ points, const float* __restrict__ W0,
    const float* __restrict__ b0, float* __restrict__ A)
{
    int row = blockIdx.x * 4 + (threadIdx.x >> 7);   // 0..1023
    int n = row >> 9, i = row & (SP - 1);
    int k = threadIdx.x & 127;
    const float* pb = points + (size_t)n * C_ * SP + i;
    float p0 = 0.f, p1 = 0.f, p2 = 0.f, p3 = 0.f;
#pragma unroll 4
    for (int c = 0; c < C_; c += 4) {
        p0 = fmaf(pb[(size_t)(c + 0) * SP], W0[(c + 0) * H1 + k], p0);
        p1 = fmaf(pb[(size_t)(c + 1) * SP], W0[(c + 1) * H1 + k], p1);
        p2 = fmaf(pb[(size_t)(c + 2) * SP], W0[(c + 2) * H1 + k], p2);
        p3 = fmaf(pb[(size_t)(c + 3) * SP], W0[(c + 3) * H1 + k], p3);
    }
    A[(size_t)row * H1 + k] = 0.5f * b0[k] + ((p0 + p1) + (p2 + p3));
}

// Split W1 (128x64) and W2 (64x32) into transposed bf16 hi/lo: WT[col][k]
__global__ __launch_bounds__(256) void k_prepW(
    const float* __restrict__ W1, const float* __restrict__ W2,
    short* __restrict__ W1Th, short* __restrict__ W1Tl,
    short* __restrict__ W2Th, short* __restrict__ W2Tl)
{
    int t0 = blockIdx.x * 256 + threadIdx.x;
    int stride = gridDim.x * 256;
    for (int idx = t0; idx < H2 * H1; idx += stride) {
        int col = idx >> 7, k = idx & 127;
        float wv = W1[k * H2 + col];
        uint32_t h = f2bf_rne(wv);
        W1Th[idx] = (short)h;
        W1Tl[idx] = (short)f2bf_rne(wv - bf2f(h));
    }
    for (int idx = t0; idx < H3 * H2; idx += stride) {
        int col = idx >> 6, k = idx & 63;
        float wv = W2[k * H3 + col];
        uint32_t h = f2bf_rne(wv);
        W2Th[idx] = (short)h;
        W2Tl[idx] = (short)f2bf_rne(wv - bf2f(h));
    }
}

// Triangular grid: blockIdx.x = u in [0,528) -> (bi<=bj). 16x16 pixel tile.
// 512 thr / 8 waves; wave w, sequential m=0,1: pixel row i = iBase+2w+m.
// X2 staged per-wave in LDS as single rne-bf16 (W2 used as hi+lo -> 2 MFMA).
// No __syncthreads until the loss reduce.
__global__ __launch_bounds__(512, 8) void k_main(
    const float* __restrict__ A,
    const short* __restrict__ W1Th, const short* __restrict__ W1Tl,
    const short* __restrict__ W2Th, const short* __restrict__ W2Tl,
    const float* __restrict__ b1, const float* __restrict__ b2,
    const float* __restrict__ W3, const float* __restrict__ b3,
    const float* __restrict__ heat, const float* __restrict__ mask,
    const float* __restrict__ pos,
    float* __restrict__ pred, float* __restrict__ accum)
{
    // unrank u -> (bi, bj), bi<=bj, row-major over upper triangle (32 tiles)
    int u = blockIdx.x;
    int bi = (int)((65.0f - sqrtf(4225.0f - 8.0f * (float)u)) * 0.5f);
    int start = bi * (65 - bi) / 2;
    while (start > u) { --bi; start = bi * (65 - bi) / 2; }
    while (u - start >= 32 - bi) { ++bi; start = bi * (65 - bi) / 2; }
    int bj = bi + (u - start);
    bool diag = (bi == bj);
    int n = blockIdx.z;
    int iBase = bi * 16, jBase = bj * 16;

    __shared__ __align__(16) char smem[8 * 2048 + 64];   // per-wave X2 (2KB) + red

    int t = threadIdx.x;
    int l = t & 63, w = t >> 6;
    int lc = l & 15, kg = l >> 4;

    const float* Abase = A + (size_t)n * SP * H1;
    const float* Aj_row = Abase + (size_t)(jBase + lc) * H1;
    char* myx2 = smem + w * 2048;

    float w3a = W3[lc], w3b = W3[16 + lc];
    float b3v = b3[0];
    float num = 0.0f, den = 0.0f;

    for (int m = 0; m < 2; ++m) {
        int irow = iBase + 2 * w + m;
        const float* Ai_row = Abase + (size_t)irow * H1;

        // ---- layer 2: C1 = relu(Ai+Aj) @ W1 + b1 (3-product split bf16) ----
        f32x4 acc[4];
#pragma unroll
        for (int cf = 0; cf < 4; ++cf) {
            float bv = b1[cf * 16 + lc];
            acc[cf] = (f32x4){bv, bv, bv, bv};
        }
#pragma unroll
        for (int ks = 0; ks < 4; ++ks) {
            const float* aj_p = Aj_row + ks * 32 + kg * 8;
            const float* ai_p = Ai_row + ks * 32 + kg * 8;
            f32x4 aj0 = *(const f32x4*)(aj_p);
            f32x4 aj1 = *(const f32x4*)(aj_p + 4);
            f32x4 ai0 = *(const f32x4*)(ai_p);
            f32x4 ai1 = *(const f32x4*)(ai_p + 4);
            s16x8 ahi, alo;
#pragma unroll
            for (int e = 0; e < 8; ++e) {
                float s = (e < 4 ? ai0[e] : ai1[e - 4]) + (e < 4 ? aj0[e] : aj1[e - 4]);
                float x = fmaxf(s, 0.0f);
                uint32_t hb = __builtin_bit_cast(uint32_t, x) & 0xFFFF0000u;
                float lof = x - __builtin_bit_cast(float, hb);
                ahi[e] = (short)(hb >> 16);
                alo[e] = (short)(__builtin_bit_cast(uint32_t, lof) >> 16);  // trunc
            }
#pragma unroll
            for (int cf = 0; cf < 4; ++cf) {
                int boff = (cf * 16 + lc) * H1 + ks * 32 + kg * 8;
                s16x8 bhi = *(const s16x8*)(W1Th + boff);
                s16x8 blo = *(const s16x8*)(W1Tl + boff);
                acc[cf] = __builtin_amdgcn_mfma_f32_16x16x32_bf16(alo, bhi, acc[cf], 0, 0, 0);
                acc[cf] = __builtin_amdgcn_mfma_f32_16x16x32_bf16(ahi, blo, acc[cf], 0, 0, 0);
                acc[cf] = __builtin_amdgcn_mfma_f32_16x16x32_bf16(ahi, bhi, acc[cf], 0, 0, 0);
            }
        }

        // ---- X2 = relu(C1) -> per-wave LDS, single rne-bf16, XOR swizzle ----
#pragma unroll
        for (int cf = 0; cf < 4; ++cf)
#pragma unroll
            for (int r = 0; r < 4; ++r) {
                int row = kg * 4 + r;            // 0..15 (m folded out)
                int col = cf * 16 + lc;
                int g = col >> 3;
                int off = row * 128 + (((g ^ (row & 7)) & 15) << 4) + (col & 7) * 2;
                float v = fmaxf(acc[cf][r], 0.0f);
                *(short*)(myx2 + off) = (short)f2bf_rne(v);
            }

        // ---- layer 3: C2 = X2 @ (W2hi + W2lo) + b2, same-wave LDS ----
        f32x4 acc2[2];
#pragma unroll
        for (int cf = 0; cf < 2; ++cf) {
            float bv = b2[cf * 16 + lc];
            acc2[cf] = (f32x4){bv, bv, bv, bv};
        }
#pragma unroll
        for (int ks = 0; ks < 2; ++ks) {
            int g = ks * 4 + kg;
            int off = lc * 128 + (((g ^ (lc & 7)) & 15) << 4);
            s16x8 xbf = *(const s16x8*)(myx2 + off);
#pragma unroll
            for (int cf = 0; cf < 2; ++cf) {
                int boff = (cf * 16 + lc) * H2 + ks * 32 + kg * 8;
                s16x8 bhi = *(const s16x8*)(W2Th + boff);
                s16x8 blo = *(const s16x8*)(W2Tl + boff);
                acc2[cf] = __builtin_amdgcn_mfma_f32_16x16x32_bf16(xbf, blo, acc2[cf], 0, 0, 0);
                acc2[cf] = __builtin_amdgcn_mfma_f32_16x16x32_bf16(xbf, bhi, acc2[cf], 0, 0, 0);
            }
        }

        // ---- layer 4 in-register + BCE (+ mirrored pixel off-diagonal) ----
        float zr0 = fmaxf(acc2[0][0], 0.0f) * w3a + fmaxf(acc2[1][0], 0.0f) * w3b;
        float zr1 = fmaxf(acc2[0][1], 0.0f) * w3a + fmaxf(acc2[1][1], 0.0f) * w3b;
        float zr2 = fmaxf(acc2[0][2], 0.0f) * w3a + fmaxf(acc2[1][2], 0.0f) * w3b;
        float zr3 = fmaxf(acc2[0][3], 0.0f) * w3a + fmaxf(acc2[1][3], 0.0f) * w3b;
#pragma unroll
        for (int off = 1; off < 16; off <<= 1) {
            zr0 += __shfl_xor(zr0, off, 64);
            zr1 += __shfl_xor(zr1, off, 64);
            zr2 += __shfl_xor(zr2, off, 64);
            zr3 += __shfl_xor(zr3, off, 64);
        }
        float zsel = zr0;
        zsel = (lc == 1) ? zr1 : zsel;
        zsel = (lc == 2) ? zr2 : zsel;
        zsel = (lc == 3) ? zr3 : zsel;
        if (lc < 4) {
            float z = zsel + b3v;
            int j = jBase + kg * 4 + lc;
            size_t idx = ((size_t)n * SP + irow) * SP + j;
            pred[idx] = z;
            float zbase = fmaxf(z, 0.0f) + __logf(1.0f + __expf(-fabsf(z)));
            float tg = heat[idx], mk = mask[idx], pm = pos[idx];
            num += (zbase - z * tg) * mk * pm;
            den += pm;
            if (!diag) {
                size_t idx2 = ((size_t)n * SP + j) * SP + irow;
                pred[idx2] = z;
                float tg2 = heat[idx2], mk2 = mask[idx2], pm2 = pos[idx2];
                num += (zbase - z * tg2) * mk2 * pm2;
                den += pm2;
            }
        }
    }

    // ---- loss reduction: wave shuffle -> LDS -> one atomic pair per block ----
#pragma unroll
    for (int off = 32; off > 0; off >>= 1) {
        num += __shfl_down(num, off, 64);
        den += __shfl_down(den, off, 64);
    }
    float* rb = (float*)(smem + 8 * 2048);
    if (l == 0) { rb[w] = num; rb[8 + w] = den; }
    __syncthreads();
    if (t == 0) {
        float sn = 0.0f, sd = 0.0f;
#pragma unroll
        for (int q = 0; q < 8; ++q) { sn += rb[q]; sd += rb[8 + q]; }
        atomicAdd(&accum[0], sn);
        atomicAdd(&accum[1], sd);
    }
}

__global__ void k_final(const float* __restrict__ accum, float* __restrict__ out)
{
    out[0] = accum[0] / accum[1];
}

extern "C" void kernel_launch(void* const* d_in, const int* in_sizes, int n_in,
                              void* d_out, int out_size, void* d_ws, size_t ws_size,
                              hipStream_t stream)
{
    const float* points = (const float*)d_in[0];
    const float* heat   = (const float*)d_in[1];
    const float* mask   = (const float*)d_in[2];
    const float* pos    = (const float*)d_in[3];
    const float* W0     = (const float*)d_in[4];
    const float* b0     = (const float*)d_in[5];
    const float* W1     = (const float*)d_in[6];
    const float* b1     = (const float*)d_in[7];
    const float* W2     = (const float*)d_in[8];
    const float* b2     = (const float*)d_in[9];
    const float* W3     = (const float*)d_in[10];
    const float* b3     = (const float*)d_in[11];

    float* pred = (float*)d_out;                        // (2,512,512)
    float* loss = pred + (size_t)N_ * SP * SP;          // scalar

    char* ws = (char*)d_ws;
    float* accum = (float*)ws;                          // [0]=num,[1]=den
    float* A     = (float*)(ws + 256);                  // 1024*128 f32 = 512 KiB
    short* W1Th  = (short*)(ws + 256 + 524288);
    short* W1Tl  = (short*)(ws + 256 + 524288 + 16384);
    short* W2Th  = (short*)(ws + 256 + 524288 + 32768);
    short* W2Tl  = (short*)(ws + 256 + 524288 + 36864);

    hipMemsetAsync(d_ws, 0, 256, stream);
    k_prepW<<<8, 256, 0, stream>>>(W1, W2, W1Th, W1Tl, W2Th, W2Tl);
    k_precompA<<<N_ * SP / 4, 512, 0, stream>>>(points, W0, b0, A);
    k_main<<<dim3(528, 1, N_), 512, 0, stream>>>(
        A, W1Th, W1Tl, W2Th, W2Tl, b1, b2, W3, b3, heat, mask, pos, pred, accum);
    k_final<<<1, 1, 0, stream>>>(accum, loss);
}

// Round 6
// 240.178 us; speedup vs baseline: 1.6181x; 1.6181x over previous
//
#include <hip/hip_runtime.h>
#include <stdint.h>

#define N_ 2
#define C_ 256
#define SP 512
#define H1 128
#define H2 64
#define H3 32

using f32x4 = __attribute__((ext_vector_type(4))) float;
using s16x8 = __attribute__((ext_vector_type(8))) short;

__device__ __forceinline__ uint32_t f2bf_rne(float x) {
    uint32_t u = __builtin_bit_cast(uint32_t, x);
    return (u + 0x7FFFu + ((u >> 16) & 1u)) >> 16;
}
__device__ __forceinline__ float bf2f(uint32_t h) {
    return __builtin_bit_cast(float, h << 16);
}

// A[n*SP+i][k] = sum_c points[n][c][i] * W0[c][k] + 0.5*b0[k]
__global__ __launch_bounds__(512) void k_precompA(
    const float* __restrict__ points, const float* __restrict__ W0,
    const float* __restrict__ b0, float* __restrict__ A)
{
    int row = blockIdx.x * 4 + (threadIdx.x >> 7);   // 0..1023
    int n = row >> 9, i = row & (SP - 1);
    int k = threadIdx.x & 127;
    const float* pb = points + (size_t)n * C_ * SP + i;
    float p0 = 0.f, p1 = 0.f, p2 = 0.f, p3 = 0.f;
#pragma unroll 4
    for (int c = 0; c < C_; c += 4) {
        p0 = fmaf(pb[(size_t)(c + 0) * SP], W0[(c + 0) * H1 + k], p0);
        p1 = fmaf(pb[(size_t)(c + 1) * SP], W0[(c + 1) * H1 + k], p1);
        p2 = fmaf(pb[(size_t)(c + 2) * SP], W0[(c + 2) * H1 + k], p2);
        p3 = fmaf(pb[(size_t)(c + 3) * SP], W0[(c + 3) * H1 + k], p3);
    }
    A[(size_t)row * H1 + k] = 0.5f * b0[k] + ((p0 + p1) + (p2 + p3));
}

// Split W1 (128x64) and W2 (64x32) into transposed bf16 hi/lo: WT[col][k]
__global__ __launch_bounds__(256) void k_prepW(
    const float* __restrict__ W1, const float* __restrict__ W2,
    short* __restrict__ W1Th, short* __restrict__ W1Tl,
    short* __restrict__ W2Th, short* __restrict__ W2Tl)
{
    int t0 = blockIdx.x * 256 + threadIdx.x;
    int stride = gridDim.x * 256;
    for (int idx = t0; idx < H2 * H1; idx += stride) {
        int col = idx >> 7, k = idx & 127;
        float wv = W1[k * H2 + col];
        uint32_t h = f2bf_rne(wv);
        W1Th[idx] = (short)h;
        W1Tl[idx] = (short)f2bf_rne(wv - bf2f(h));
    }
    for (int idx = t0; idx < H3 * H2; idx += stride) {
        int col = idx >> 6, k = idx & 63;
        float wv = W2[k * H3 + col];
        uint32_t h = f2bf_rne(wv);
        W2Th[idx] = (short)h;
        W2Tl[idx] = (short)f2bf_rne(wv - bf2f(h));
    }
}

// Triangular grid: blockIdx.x = u in [0,528) -> (bi<=bj). 16x16 pixel tile.
// 512 thr / 8 waves; wave w, sequential m=0,1: pixel row i = iBase+2w+m.
// X2 staged per-wave in LDS as single rne-bf16 (W2 used as hi+lo -> 2 MFMA).
// No __syncthreads until the loss reduce.
// NOTE launch bounds (512,4): R5's (512,8) forced a 32-VGPR cap -> full spill
// (515 MB scratch writes, 371 us). Do not tighten.
__global__ __launch_bounds__(512, 4) void k_main(
    const float* __restrict__ A,
    const short* __restrict__ W1Th, const short* __restrict__ W1Tl,
    const short* __restrict__ W2Th, const short* __restrict__ W2Tl,
    const float* __restrict__ b1, const float* __restrict__ b2,
    const float* __restrict__ W3, const float* __restrict__ b3,
    const float* __restrict__ heat, const float* __restrict__ mask,
    const float* __restrict__ pos,
    float* __restrict__ pred, float* __restrict__ accum)
{
    // unrank u -> (bi, bj), bi<=bj, row-major over upper triangle (32 tiles)
    int u = blockIdx.x;
    int bi = (int)((65.0f - sqrtf(4225.0f - 8.0f * (float)u)) * 0.5f);
    int start = bi * (65 - bi) / 2;
    while (start > u) { --bi; start = bi * (65 - bi) / 2; }
    while (u - start >= 32 - bi) { ++bi; start = bi * (65 - bi) / 2; }
    int bj = bi + (u - start);
    bool diag = (bi == bj);
    int n = blockIdx.z;
    int iBase = bi * 16, jBase = bj * 16;

    __shared__ __align__(16) char smem[8 * 2048 + 64];   // per-wave X2 (2KB) + red

    int t = threadIdx.x;
    int l = t & 63, w = t >> 6;
    int lc = l & 15, kg = l >> 4;

    const float* Abase = A + (size_t)n * SP * H1;
    const float* Aj_row = Abase + (size_t)(jBase + lc) * H1;
    char* myx2 = smem + w * 2048;

    float w3a = W3[lc], w3b = W3[16 + lc];
    float b3v = b3[0];
    float num = 0.0f, den = 0.0f;

    for (int m = 0; m < 2; ++m) {
        int irow = iBase + 2 * w + m;
        const float* Ai_row = Abase + (size_t)irow * H1;

        // ---- layer 2: C1 = relu(Ai+Aj) @ W1 + b1 (3-product split bf16) ----
        f32x4 acc[4];
#pragma unroll
        for (int cf = 0; cf < 4; ++cf) {
            float bv = b1[cf * 16 + lc];
            acc[cf] = (f32x4){bv, bv, bv, bv};
        }
#pragma unroll
        for (int ks = 0; ks < 4; ++ks) {
            const float* aj_p = Aj_row + ks * 32 + kg * 8;
            const float* ai_p = Ai_row + ks * 32 + kg * 8;
            f32x4 aj0 = *(const f32x4*)(aj_p);
            f32x4 aj1 = *(const f32x4*)(aj_p + 4);
            f32x4 ai0 = *(const f32x4*)(ai_p);
            f32x4 ai1 = *(const f32x4*)(ai_p + 4);
            s16x8 ahi, alo;
#pragma unroll
            for (int e = 0; e < 8; ++e) {
                float s = (e < 4 ? ai0[e] : ai1[e - 4]) + (e < 4 ? aj0[e] : aj1[e - 4]);
                float x = fmaxf(s, 0.0f);
                uint32_t hb = __builtin_bit_cast(uint32_t, x) & 0xFFFF0000u;
                float lof = x - __builtin_bit_cast(float, hb);
                ahi[e] = (short)(hb >> 16);
                alo[e] = (short)(__builtin_bit_cast(uint32_t, lof) >> 16);  // trunc
            }
#pragma unroll
            for (int cf = 0; cf < 4; ++cf) {
                int boff = (cf * 16 + lc) * H1 + ks * 32 + kg * 8;
                s16x8 bhi = *(const s16x8*)(W1Th + boff);
                s16x8 blo = *(const s16x8*)(W1Tl + boff);
                acc[cf] = __builtin_amdgcn_mfma_f32_16x16x32_bf16(alo, bhi, acc[cf], 0, 0, 0);
                acc[cf] = __builtin_amdgcn_mfma_f32_16x16x32_bf16(ahi, blo, acc[cf], 0, 0, 0);
                acc[cf] = __builtin_amdgcn_mfma_f32_16x16x32_bf16(ahi, bhi, acc[cf], 0, 0, 0);
            }
        }

        // ---- X2 = relu(C1) -> per-wave LDS, single rne-bf16, XOR swizzle ----
#pragma unroll
        for (int cf = 0; cf < 4; ++cf)
#pragma unroll
            for (int r = 0; r < 4; ++r) {
                int row = kg * 4 + r;            // 0..15 (m folded out)
                int col = cf * 16 + lc;
                int g = col >> 3;
                int off = row * 128 + (((g ^ (row & 7)) & 15) << 4) + (col & 7) * 2;
                float v = fmaxf(acc[cf][r], 0.0f);
                *(short*)(myx2 + off) = (short)f2bf_rne(v);
            }

        // ---- layer 3: C2 = X2 @ (W2hi + W2lo) + b2, same-wave LDS ----
        f32x4 acc2[2];
#pragma unroll
        for (int cf = 0; cf < 2; ++cf) {
            float bv = b2[cf * 16 + lc];
            acc2[cf] = (f32x4){bv, bv, bv, bv};
        }
#pragma unroll
        for (int ks = 0; ks < 2; ++ks) {
            int g = ks * 4 + kg;
            int off = lc * 128 + (((g ^ (lc & 7)) & 15) << 4);
            s16x8 xbf = *(const s16x8*)(myx2 + off);
#pragma unroll
            for (int cf = 0; cf < 2; ++cf) {
                int boff = (cf * 16 + lc) * H2 + ks * 32 + kg * 8;
                s16x8 bhi = *(const s16x8*)(W2Th + boff);
                s16x8 blo = *(const s16x8*)(W2Tl + boff);
                acc2[cf] = __builtin_amdgcn_mfma_f32_16x16x32_bf16(xbf, blo, acc2[cf], 0, 0, 0);
                acc2[cf] = __builtin_amdgcn_mfma_f32_16x16x32_bf16(xbf, bhi, acc2[cf], 0, 0, 0);
            }
        }

        // ---- layer 4 in-register + BCE (+ mirrored pixel off-diagonal) ----
        float zr0 = fmaxf(acc2[0][0], 0.0f) * w3a + fmaxf(acc2[1][0], 0.0f) * w3b;
        float zr1 = fmaxf(acc2[0][1], 0.0f) * w3a + fmaxf(acc2[1][1], 0.0f) * w3b;
        float zr2 = fmaxf(acc2[0][2], 0.0f) * w3a + fmaxf(acc2[1][2], 0.0f) * w3b;
        float zr3 = fmaxf(acc2[0][3], 0.0f) * w3a + fmaxf(acc2[1][3], 0.0f) * w3b;
#pragma unroll
        for (int off = 1; off < 16; off <<= 1) {
            zr0 += __shfl_xor(zr0, off, 64);
            zr1 += __shfl_xor(zr1, off, 64);
            zr2 += __shfl_xor(zr2, off, 64);
            zr3 += __shfl_xor(zr3, off, 64);
        }
        float zsel = zr0;
        zsel = (lc == 1) ? zr1 : zsel;
        zsel = (lc == 2) ? zr2 : zsel;
        zsel = (lc == 3) ? zr3 : zsel;
        if (lc < 4) {
            float z = zsel + b3v;
            int j = jBase + kg * 4 + lc;
            size_t idx = ((size_t)n * SP + irow) * SP + j;
            pred[idx] = z;
            float zbase = fmaxf(z, 0.0f) + __logf(1.0f + __expf(-fabsf(z)));
            float tg = heat[idx], mk = mask[idx], pm = pos[idx];
            num += (zbase - z * tg) * mk * pm;
            den += pm;
            if (!diag) {
                size_t idx2 = ((size_t)n * SP + j) * SP + irow;
                pred[idx2] = z;
                float tg2 = heat[idx2], mk2 = mask[idx2], pm2 = pos[idx2];
                num += (zbase - z * tg2) * mk2 * pm2;
                den += pm2;
            }
        }
    }

    // ---- loss reduction: wave shuffle -> LDS -> one atomic pair per block ----
#pragma unroll
    for (int off = 32; off > 0; off >>= 1) {
        num += __shfl_down(num, off, 64);
        den += __shfl_down(den, off, 64);
    }
    float* rb = (float*)(smem + 8 * 2048);
    if (l == 0) { rb[w] = num; rb[8 + w] = den; }
    __syncthreads();
    if (t == 0) {
        float sn = 0.0f, sd = 0.0f;
#pragma unroll
        for (int q = 0; q < 8; ++q) { sn += rb[q]; sd += rb[8 + q]; }
        atomicAdd(&accum[0], sn);
        atomicAdd(&accum[1], sd);
    }
}

__global__ void k_final(const float* __restrict__ accum, float* __restrict__ out)
{
    out[0] = accum[0] / accum[1];
}

extern "C" void kernel_launch(void* const* d_in, const int* in_sizes, int n_in,
                              void* d_out, int out_size, void* d_ws, size_t ws_size,
                              hipStream_t stream)
{
    const float* points = (const float*)d_in[0];
    const float* heat   = (const float*)d_in[1];
    const float* mask   = (const float*)d_in[2];
    const float* pos    = (const float*)d_in[3];
    const float* W0     = (const float*)d_in[4];
    const float* b0     = (const float*)d_in[5];
    const float* W1     = (const float*)d_in[6];
    const float* b1     = (const float*)d_in[7];
    const float* W2     = (const float*)d_in[8];
    const float* b2     = (const float*)d_in[9];
    const float* W3     = (const float*)d_in[10];
    const float* b3     = (const float*)d_in[11];

    float* pred = (float*)d_out;                        // (2,512,512)
    float* loss = pred + (size_t)N_ * SP * SP;          // scalar

    char* ws = (char*)d_ws;
    float* accum = (float*)ws;                          // [0]=num,[1]=den
    float* A     = (float*)(ws + 256);                  // 1024*128 f32 = 512 KiB
    short* W1Th  = (short*)(ws + 256 + 524288);
    short* W1Tl  = (short*)(ws + 256 + 524288 + 16384);
    short* W2Th  = (short*)(ws + 256 + 524288 + 32768);
    short* W2Tl  = (short*)(ws + 256 + 524288 + 36864);

    hipMemsetAsync(d_ws, 0, 256, stream);
    k_prepW<<<8, 256, 0, stream>>>(W1, W2, W1Th, W1Tl, W2Th, W2Tl);
    k_precompA<<<N_ * SP / 4, 512, 0, stream>>>(points, W0, b0, A);
    k_main<<<dim3(528, 1, N_), 512, 0, stream>>>(
        A, W1Th, W1Tl, W2Th, W2Tl, b1, b2, W3, b3, heat, mask, pos, pred, accum);
    k_final<<<1, 1, 0, stream>>>(accum, loss);
}

// Round 7
// 128.775 us; speedup vs baseline: 3.0179x; 1.8651x over previous
//
#include <hip/hip_runtime.h>
#include <stdint.h>

#define N_ 2
#define C_ 256
#define SP 512
#define H1 128
#define H2 64
#define H3 32

using f32x4 = __attribute__((ext_vector_type(4))) float;
using s16x8 = __attribute__((ext_vector_type(8))) short;

__device__ __forceinline__ uint32_t f2bf_rne(float x) {
    uint32_t u = __builtin_bit_cast(uint32_t, x);
    return (u + 0x7FFFu + ((u >> 16) & 1u)) >> 16;
}
__device__ __forceinline__ float bf2f(uint32_t h) {
    return __builtin_bit_cast(float, h << 16);
}

// A[n*SP+i][k] = sum_c points[n][c][i] * W0[c][k] + 0.5*b0[k]
__global__ __launch_bounds__(512) void k_precompA(
    const float* __restrict__ points, const float* __restrict__ W0,
    const float* __restrict__ b0, float* __restrict__ A)
{
    int row = blockIdx.x * 4 + (threadIdx.x >> 7);   // 0..1023
    int n = row >> 9, i = row & (SP - 1);
    int k = threadIdx.x & 127;
    const float* pb = points + (size_t)n * C_ * SP + i;
    float p0 = 0.f, p1 = 0.f, p2 = 0.f, p3 = 0.f;
#pragma unroll 4
    for (int c = 0; c < C_; c += 4) {
        p0 = fmaf(pb[(size_t)(c + 0) * SP], W0[(c + 0) * H1 + k], p0);
        p1 = fmaf(pb[(size_t)(c + 1) * SP], W0[(c + 1) * H1 + k], p1);
        p2 = fmaf(pb[(size_t)(c + 2) * SP], W0[(c + 2) * H1 + k], p2);
        p3 = fmaf(pb[(size_t)(c + 3) * SP], W0[(c + 3) * H1 + k], p3);
    }
    A[(size_t)row * H1 + k] = 0.5f * b0[k] + ((p0 + p1) + (p2 + p3));
}

// Split W1 (128x64) and W2 (64x32) into transposed bf16 hi/lo: WT[col][k]
__global__ __launch_bounds__(256) void k_prepW(
    const float* __restrict__ W1, const float* __restrict__ W2,
    short* __restrict__ W1Th, short* __restrict__ W1Tl,
    short* __restrict__ W2Th, short* __restrict__ W2Tl)
{
    int t0 = blockIdx.x * 256 + threadIdx.x;
    int stride = gridDim.x * 256;
    for (int idx = t0; idx < H2 * H1; idx += stride) {
        int col = idx >> 7, k = idx & 127;
        float wv = W1[k * H2 + col];
        uint32_t h = f2bf_rne(wv);
        W1Th[idx] = (short)h;
        W1Tl[idx] = (short)f2bf_rne(wv - bf2f(h));
    }
    for (int idx = t0; idx < H3 * H2; idx += stride) {
        int col = idx >> 6, k = idx & 63;
        float wv = W2[k * H3 + col];
        uint32_t h = f2bf_rne(wv);
        W2Th[idx] = (short)h;
        W2Tl[idx] = (short)f2bf_rne(wv - bf2f(h));
    }
}

// Triangular grid: blockIdx.x = u in [0,528) -> (bi<=bj). 16x16 pixel tile.
// 512 thr / 8 waves; wave w, sequential m=0,1: pixel row i = iBase+2w+m.
// X2 staged per-wave in LDS as single rne-bf16 (W2 used as hi+lo -> 2 MFMA).
// No __syncthreads until the loss reduce.
//
// LAUNCH BOUNDS HISTORY (do not tighten):
//   (512,8) -> VGPR capped 32, 515 MB scratch, 371 us   [R5]
//   (512,4) -> VGPR capped 64, 366 MB scratch, 224 us   [R6]
//   empirical cap = 256/min_waves; kernel needs ~100-115 VGPR -> use (512,2).
__global__ __launch_bounds__(512, 2) void k_main(
    const float* __restrict__ A,
    const short* __restrict__ W1Th, const short* __restrict__ W1Tl,
    const short* __restrict__ W2Th, const short* __restrict__ W2Tl,
    const float* __restrict__ b1, const float* __restrict__ b2,
    const float* __restrict__ W3, const float* __restrict__ b3,
    const float* __restrict__ heat, const float* __restrict__ mask,
    const float* __restrict__ pos,
    float* __restrict__ pred, float* __restrict__ accum)
{
    // unrank u -> (bi, bj), bi<=bj, row-major over upper triangle (32 tiles)
    int u = blockIdx.x;
    int bi = (int)((65.0f - sqrtf(4225.0f - 8.0f * (float)u)) * 0.5f);
    int start = bi * (65 - bi) / 2;
    while (start > u) { --bi; start = bi * (65 - bi) / 2; }
    while (u - start >= 32 - bi) { ++bi; start = bi * (65 - bi) / 2; }
    int bj = bi + (u - start);
    bool diag = (bi == bj);
    int n = blockIdx.z;
    int iBase = bi * 16, jBase = bj * 16;

    __shared__ __align__(16) char smem[8 * 2048 + 64];   // per-wave X2 (2KB) + red

    int t = threadIdx.x;
    int l = t & 63, w = t >> 6;
    int lc = l & 15, kg = l >> 4;

    const float* Abase = A + (size_t)n * SP * H1;
    const float* Aj_row = Abase + (size_t)(jBase + lc) * H1;
    char* myx2 = smem + w * 2048;

    float w3a = W3[lc], w3b = W3[16 + lc];
    float b3v = b3[0];
    float num = 0.0f, den = 0.0f;

#pragma unroll 1
    for (int m = 0; m < 2; ++m) {
        int irow = iBase + 2 * w + m;
        const float* Ai_row = Abase + (size_t)irow * H1;

        // ---- layer 2: C1 = relu(Ai+Aj) @ W1 + b1 (3-product split bf16) ----
        f32x4 acc[4];
#pragma unroll
        for (int cf = 0; cf < 4; ++cf) {
            float bv = b1[cf * 16 + lc];
            acc[cf] = (f32x4){bv, bv, bv, bv};
        }
#pragma unroll
        for (int ks = 0; ks < 4; ++ks) {
            const float* aj_p = Aj_row + ks * 32 + kg * 8;
            const float* ai_p = Ai_row + ks * 32 + kg * 8;
            f32x4 aj0 = *(const f32x4*)(aj_p);
            f32x4 aj1 = *(const f32x4*)(aj_p + 4);
            f32x4 ai0 = *(const f32x4*)(ai_p);
            f32x4 ai1 = *(const f32x4*)(ai_p + 4);
            s16x8 ahi, alo;
#pragma unroll
            for (int e = 0; e < 8; ++e) {
                float s = (e < 4 ? ai0[e] : ai1[e - 4]) + (e < 4 ? aj0[e] : aj1[e - 4]);
                float x = fmaxf(s, 0.0f);
                uint32_t hb = __builtin_bit_cast(uint32_t, x) & 0xFFFF0000u;
                float lof = x - __builtin_bit_cast(float, hb);
                ahi[e] = (short)(hb >> 16);
                alo[e] = (short)(__builtin_bit_cast(uint32_t, lof) >> 16);  // trunc
            }
#pragma unroll
            for (int cf = 0; cf < 4; ++cf) {
                int boff = (cf * 16 + lc) * H1 + ks * 32 + kg * 8;
                s16x8 bhi = *(const s16x8*)(W1Th + boff);
                s16x8 blo = *(const s16x8*)(W1Tl + boff);
                acc[cf] = __builtin_amdgcn_mfma_f32_16x16x32_bf16(alo, bhi, acc[cf], 0, 0, 0);
                acc[cf] = __builtin_amdgcn_mfma_f32_16x16x32_bf16(ahi, blo, acc[cf], 0, 0, 0);
                acc[cf] = __builtin_amdgcn_mfma_f32_16x16x32_bf16(ahi, bhi, acc[cf], 0, 0, 0);
            }
        }

        // ---- X2 = relu(C1) -> per-wave LDS, single rne-bf16, XOR swizzle ----
#pragma unroll
        for (int cf = 0; cf < 4; ++cf)
#pragma unroll
            for (int r = 0; r < 4; ++r) {
                int row = kg * 4 + r;            // 0..15 (m folded out)
                int col = cf * 16 + lc;
                int g = col >> 3;
                int off = row * 128 + (((g ^ (row & 7)) & 15) << 4) + (col & 7) * 2;
                float v = fmaxf(acc[cf][r], 0.0f);
                *(short*)(myx2 + off) = (short)f2bf_rne(v);
            }

        // ---- layer 3: C2 = X2 @ (W2hi + W2lo) + b2, same-wave LDS ----
        f32x4 acc2[2];
#pragma unroll
        for (int cf = 0; cf < 2; ++cf) {
            float bv = b2[cf * 16 + lc];
            acc2[cf] = (f32x4){bv, bv, bv, bv};
        }
#pragma unroll
        for (int ks = 0; ks < 2; ++ks) {
            int g = ks * 4 + kg;
            int off = lc * 128 + (((g ^ (lc & 7)) & 15) << 4);
            s16x8 xbf = *(const s16x8*)(myx2 + off);
#pragma unroll
            for (int cf = 0; cf < 2; ++cf) {
                int boff = (cf * 16 + lc) * H2 + ks * 32 + kg * 8;
                s16x8 bhi = *(const s16x8*)(W2Th + boff);
                s16x8 blo = *(const s16x8*)(W2Tl + boff);
                acc2[cf] = __builtin_amdgcn_mfma_f32_16x16x32_bf16(xbf, blo, acc2[cf], 0, 0, 0);
                acc2[cf] = __builtin_amdgcn_mfma_f32_16x16x32_bf16(xbf, bhi, acc2[cf], 0, 0, 0);
            }
        }

        // ---- layer 4 in-register + BCE (+ mirrored pixel off-diagonal) ----
        float zr0 = fmaxf(acc2[0][0], 0.0f) * w3a + fmaxf(acc2[1][0], 0.0f) * w3b;
        float zr1 = fmaxf(acc2[0][1], 0.0f) * w3a + fmaxf(acc2[1][1], 0.0f) * w3b;
        float zr2 = fmaxf(acc2[0][2], 0.0f) * w3a + fmaxf(acc2[1][2], 0.0f) * w3b;
        float zr3 = fmaxf(acc2[0][3], 0.0f) * w3a + fmaxf(acc2[1][3], 0.0f) * w3b;
#pragma unroll
        for (int off = 1; off < 16; off <<= 1) {
            zr0 += __shfl_xor(zr0, off, 64);
            zr1 += __shfl_xor(zr1, off, 64);
            zr2 += __shfl_xor(zr2, off, 64);
            zr3 += __shfl_xor(zr3, off, 64);
        }
        float zsel = zr0;
        zsel = (lc == 1) ? zr1 : zsel;
        zsel = (lc == 2) ? zr2 : zsel;
        zsel = (lc == 3) ? zr3 : zsel;
        if (lc < 4) {
            float z = zsel + b3v;
            int j = jBase + kg * 4 + lc;
            size_t idx = ((size_t)n * SP + irow) * SP + j;
            pred[idx] = z;
            float zbase = fmaxf(z, 0.0f) + __logf(1.0f + __expf(-fabsf(z)));
            float tg = heat[idx], mk = mask[idx], pm = pos[idx];
            num += (zbase - z * tg) * mk * pm;
            den += pm;
            if (!diag) {
                size_t idx2 = ((size_t)n * SP + j) * SP + irow;
                pred[idx2] = z;
                float tg2 = heat[idx2], mk2 = mask[idx2], pm2 = pos[idx2];
                num += (zbase - z * tg2) * mk2 * pm2;
                den += pm2;
            }
        }
    }

    // ---- loss reduction: wave shuffle -> LDS -> one atomic pair per block ----
#pragma unroll
    for (int off = 32; off > 0; off >>= 1) {
        num += __shfl_down(num, off, 64);
        den += __shfl_down(den, off, 64);
    }
    float* rb = (float*)(smem + 8 * 2048);
    if (l == 0) { rb[w] = num; rb[8 + w] = den; }
    __syncthreads();
    if (t == 0) {
        float sn = 0.0f, sd = 0.0f;
#pragma unroll
        for (int q = 0; q < 8; ++q) { sn += rb[q]; sd += rb[8 + q]; }
        atomicAdd(&accum[0], sn);
        atomicAdd(&accum[1], sd);
    }
}

__global__ void k_final(const float* __restrict__ accum, float* __restrict__ out)
{
    out[0] = accum[0] / accum[1];
}

extern "C" void kernel_launch(void* const* d_in, const int* in_sizes, int n_in,
                              void* d_out, int out_size, void* d_ws, size_t ws_size,
                              hipStream_t stream)
{
    const float* points = (const float*)d_in[0];
    const float* heat   = (const float*)d_in[1];
    const float* mask   = (const float*)d_in[2];
    const float* pos    = (const float*)d_in[3];
    const float* W0     = (const float*)d_in[4];
    const float* b0     = (const float*)d_in[5];
    const float* W1     = (const float*)d_in[6];
    const float* b1     = (const float*)d_in[7];
    const float* W2     = (const float*)d_in[8];
    const float* b2     = (const float*)d_in[9];
    const float* W3     = (const float*)d_in[10];
    const float* b3     = (const float*)d_in[11];

    float* pred = (float*)d_out;                        // (2,512,512)
    float* loss = pred + (size_t)N_ * SP * SP;          // scalar

    char* ws = (char*)d_ws;
    float* accum = (float*)ws;                          // [0]=num,[1]=den
    float* A     = (float*)(ws + 256);                  // 1024*128 f32 = 512 KiB
    short* W1Th  = (short*)(ws + 256 + 524288);
    short* W1Tl  = (short*)(ws + 256 + 524288 + 16384);
    short* W2Th  = (short*)(ws + 256 + 524288 + 32768);
    short* W2Tl  = (short*)(ws + 256 + 524288 + 36864);

    hipMemsetAsync(d_ws, 0, 256, stream);
    k_prepW<<<8, 256, 0, stream>>>(W1, W2, W1Th, W1Tl, W2Th, W2Tl);
    k_precompA<<<N_ * SP / 4, 512, 0, stream>>>(points, W0, b0, A);
    k_main<<<dim3(528, 1, N_), 512, 0, stream>>>(
        A, W1Th, W1Tl, W2Th, W2Tl, b1, b2, W3, b3, heat, mask, pos, pred, accum);
    k_final<<<1, 1, 0, stream>>>(accum, loss);
}

// Round 8
// 99.052 us; speedup vs baseline: 3.9235x; 1.3001x over previous
//
#include <hip/hip_runtime.h>
#include <stdint.h>

#define N_ 2
#define C_ 256
#define SP 512
#define H1 128
#define H2 64
#define H3 32

using f32x4 = __attribute__((ext_vector_type(4))) float;
using s16x8 = __attribute__((ext_vector_type(8))) short;

__device__ __forceinline__ uint32_t f2bf_rne(float x) {
    uint32_t u = __builtin_bit_cast(uint32_t, x);
    return (u + 0x7FFFu + ((u >> 16) & 1u)) >> 16;
}
__device__ __forceinline__ float bf2f(uint32_t h) {
    return __builtin_bit_cast(float, h << 16);
}

// A[n*SP+i][k] = sum_c points[n][c][i] * W0[c][k] + 0.5*b0[k]
__global__ __launch_bounds__(512) void k_precompA(
    const float* __restrict__ points, const float* __restrict__ W0,
    const float* __restrict__ b0, float* __restrict__ A)
{
    int row = blockIdx.x * 4 + (threadIdx.x >> 7);   // 0..1023
    int n = row >> 9, i = row & (SP - 1);
    int k = threadIdx.x & 127;
    const float* pb = points + (size_t)n * C_ * SP + i;
    float p0 = 0.f, p1 = 0.f, p2 = 0.f, p3 = 0.f;
#pragma unroll 4
    for (int c = 0; c < C_; c += 4) {
        p0 = fmaf(pb[(size_t)(c + 0) * SP], W0[(c + 0) * H1 + k], p0);
        p1 = fmaf(pb[(size_t)(c + 1) * SP], W0[(c + 1) * H1 + k], p1);
        p2 = fmaf(pb[(size_t)(c + 2) * SP], W0[(c + 2) * H1 + k], p2);
        p3 = fmaf(pb[(size_t)(c + 3) * SP], W0[(c + 3) * H1 + k], p3);
    }
    A[(size_t)row * H1 + k] = 0.5f * b0[k] + ((p0 + p1) + (p2 + p3));
}

// Split W1 (128x64) and W2 (64x32) into transposed bf16 hi/lo: WT[col][k]
__global__ __launch_bounds__(256) void k_prepW(
    const float* __restrict__ W1, const float* __restrict__ W2,
    short* __restrict__ W1Th, short* __restrict__ W1Tl,
    short* __restrict__ W2Th, short* __restrict__ W2Tl)
{
    int t0 = blockIdx.x * 256 + threadIdx.x;
    int stride = gridDim.x * 256;
    for (int idx = t0; idx < H2 * H1; idx += stride) {
        int col = idx >> 7, k = idx & 127;
        float wv = W1[k * H2 + col];
        uint32_t h = f2bf_rne(wv);
        W1Th[idx] = (short)h;
        W1Tl[idx] = (short)f2bf_rne(wv - bf2f(h));
    }
    for (int idx = t0; idx < H3 * H2; idx += stride) {
        int col = idx >> 6, k = idx & 63;
        float wv = W2[k * H3 + col];
        uint32_t h = f2bf_rne(wv);
        W2Th[idx] = (short)h;
        W2Tl[idx] = (short)f2bf_rne(wv - bf2f(h));
    }
}

// Triangular grid: u in [0,528) -> (bi<=bj). 16x16 pixel tile, 512 thr/8 waves.
// Wave w handles i-rows {iBase+2w, iBase+2w+1} INTERLEAVED (2x MFMA ILP);
// MFMA A-rows are the 16 j-pixels. X2 per-wave in LDS (single rne-bf16).
// NO epilogue here: z-tile -> LDS -> coalesced stores of both triangle halves.
// BCE/loss moved to k_loss (streaming).  Launch-bounds history: (512,8)->32reg
// spill 515MB; (512,4)->64reg spill 366MB; (512,2) cap 128 is the floor.
__global__ __launch_bounds__(512, 2) void k_main(
    const float* __restrict__ A,
    const short* __restrict__ W1Th, const short* __restrict__ W1Tl,
    const short* __restrict__ W2Th, const short* __restrict__ W2Tl,
    const float* __restrict__ b1, const float* __restrict__ b2,
    const float* __restrict__ W3, const float* __restrict__ b3,
    float* __restrict__ pred)
{
    // unrank u -> (bi, bj), bi<=bj (32x32 tile triangle)
    int u = blockIdx.x;
    int bi = (int)((65.0f - sqrtf(4225.0f - 8.0f * (float)u)) * 0.5f);
    int start = bi * (65 - bi) / 2;
    while (start > u) { --bi; start = bi * (65 - bi) / 2; }
    while (u - start >= 32 - bi) { ++bi; start = bi * (65 - bi) / 2; }
    int bj = bi + (u - start);
    bool diag = (bi == bj);
    int n = blockIdx.z;
    int iBase = bi * 16, jBase = bj * 16;

    // LDS: per-wave X2 [32 rows][64 cols] bf16 swizzled (4KB) ; z-tile 16x17 f32
    __shared__ __align__(16) char smem[8 * 4096 + 16 * 17 * 4];
    float* zb = (float*)(smem + 8 * 4096);

    int t = threadIdx.x;
    int l = t & 63, w = t >> 6;
    int lc = l & 15, kg = l >> 4;

    const float* Abase = A + (size_t)n * SP * H1;
    const float* Aj_row = Abase + (size_t)(jBase + lc) * H1;   // j-pixel per lane
    const float* Ai0_row = Abase + (size_t)(iBase + 2 * w) * H1;
    const float* Ai1_row = Abase + (size_t)(iBase + 2 * w + 1) * H1;
    char* myx2 = smem + w * 4096;

    // ---- layer 2: C1[m] = relu(Ai_m + Aj) @ W1 + b1 (3-product split bf16) ----
    f32x4 acc[2][4];
#pragma unroll
    for (int cf = 0; cf < 4; ++cf) {
        float bv = b1[cf * 16 + lc];
        acc[0][cf] = (f32x4){bv, bv, bv, bv};
        acc[1][cf] = (f32x4){bv, bv, bv, bv};
    }
#pragma unroll
    for (int ks = 0; ks < 4; ++ks) {
        const float* aj_p = Aj_row + ks * 32 + kg * 8;
        f32x4 aj0 = *(const f32x4*)(aj_p);
        f32x4 aj1 = *(const f32x4*)(aj_p + 4);
        s16x8 ahi[2], alo[2];
#pragma unroll
        for (int m = 0; m < 2; ++m) {
            const float* ai_p = (m ? Ai1_row : Ai0_row) + ks * 32 + kg * 8;
            f32x4 ai0 = *(const f32x4*)(ai_p);
            f32x4 ai1 = *(const f32x4*)(ai_p + 4);
#pragma unroll
            for (int e = 0; e < 8; ++e) {
                float s = (e < 4 ? ai0[e] : ai1[e - 4]) + (e < 4 ? aj0[e] : aj1[e - 4]);
                float x = fmaxf(s, 0.0f);
                uint32_t hb = __builtin_bit_cast(uint32_t, x) & 0xFFFF0000u;
                float lof = x - __builtin_bit_cast(float, hb);
                ahi[m][e] = (short)(hb >> 16);
                alo[m][e] = (short)(__builtin_bit_cast(uint32_t, lof) >> 16);
            }
        }
#pragma unroll
        for (int cf = 0; cf < 4; ++cf) {
            int boff = (cf * 16 + lc) * H1 + ks * 32 + kg * 8;
            s16x8 bhi = *(const s16x8*)(W1Th + boff);
            s16x8 blo = *(const s16x8*)(W1Tl + boff);
#pragma unroll
            for (int m = 0; m < 2; ++m) {
                acc[m][cf] = __builtin_amdgcn_mfma_f32_16x16x32_bf16(alo[m], bhi, acc[m][cf], 0, 0, 0);
                acc[m][cf] = __builtin_amdgcn_mfma_f32_16x16x32_bf16(ahi[m], blo, acc[m][cf], 0, 0, 0);
                acc[m][cf] = __builtin_amdgcn_mfma_f32_16x16x32_bf16(ahi[m], bhi, acc[m][cf], 0, 0, 0);
            }
        }
    }

    // ---- X2 = relu(C1) -> per-wave LDS [row=m*16+jpix][col], rne-bf16, swz ----
#pragma unroll
    for (int m = 0; m < 2; ++m)
#pragma unroll
        for (int cf = 0; cf < 4; ++cf)
#pragma unroll
            for (int r = 0; r < 4; ++r) {
                int row = m * 16 + kg * 4 + r;       // j-pixel (D: row=(l>>4)*4+reg)
                int col = cf * 16 + lc;              // hidden col (D: col=l&15)
                int g = col >> 3;
                int off = row * 128 + (((g ^ (row & 7))) << 4) + (col & 7) * 2;
                *(short*)(myx2 + off) = (short)f2bf_rne(fmaxf(acc[m][cf][r], 0.0f));
            }

    // ---- layer 3: C2[m] = X2[m] @ (W2hi + W2lo) + b2 (same-wave LDS) ----
    f32x4 acc2[2][2];
#pragma unroll
    for (int cf = 0; cf < 2; ++cf) {
        float bv = b2[cf * 16 + lc];
        acc2[0][cf] = (f32x4){bv, bv, bv, bv};
        acc2[1][cf] = (f32x4){bv, bv, bv, bv};
    }
#pragma unroll
    for (int ks = 0; ks < 2; ++ks) {
#pragma unroll
        for (int m = 0; m < 2; ++m) {
            int row = m * 16 + lc;                   // A: row=l&15 -> j-pixel lc
            int g = ks * 4 + kg;
            int off = row * 128 + (((g ^ (row & 7))) << 4);
            s16x8 xbf = *(const s16x8*)(myx2 + off);
#pragma unroll
            for (int cf = 0; cf < 2; ++cf) {
                int boff = (cf * 16 + lc) * H2 + ks * 32 + kg * 8;
                s16x8 bhi = *(const s16x8*)(W2Th + boff);
                s16x8 blo = *(const s16x8*)(W2Tl + boff);
                acc2[m][cf] = __builtin_amdgcn_mfma_f32_16x16x32_bf16(xbf, blo, acc2[m][cf], 0, 0, 0);
                acc2[m][cf] = __builtin_amdgcn_mfma_f32_16x16x32_bf16(xbf, bhi, acc2[m][cf], 0, 0, 0);
            }
        }
    }

    // ---- layer 4: z = relu(a3) . W3 + b3, in-register; z -> LDS z-tile ----
    float w3a = W3[lc], w3b = W3[16 + lc];
    float b3v = b3[0];
#pragma unroll
    for (int m = 0; m < 2; ++m) {
        float zr0 = fmaxf(acc2[m][0][0], 0.0f) * w3a + fmaxf(acc2[m][1][0], 0.0f) * w3b;
        float zr1 = fmaxf(acc2[m][0][1], 0.0f) * w3a + fmaxf(acc2[m][1][1], 0.0f) * w3b;
        float zr2 = fmaxf(acc2[m][0][2], 0.0f) * w3a + fmaxf(acc2[m][1][2], 0.0f) * w3b;
        float zr3 = fmaxf(acc2[m][0][3], 0.0f) * w3a + fmaxf(acc2[m][1][3], 0.0f) * w3b;
#pragma unroll
        for (int off = 1; off < 16; off <<= 1) {     // sum over a3 cols (lc)
            zr0 += __shfl_xor(zr0, off, 64);
            zr1 += __shfl_xor(zr1, off, 64);
            zr2 += __shfl_xor(zr2, off, 64);
            zr3 += __shfl_xor(zr3, off, 64);
        }
        float zsel = zr0;
        zsel = (lc == 1) ? zr1 : zsel;
        zsel = (lc == 2) ? zr2 : zsel;
        zsel = (lc == 3) ? zr3 : zsel;
        if (lc < 4) {
            int jpix = kg * 4 + lc;
            zb[(2 * w + m) * 17 + jpix] = zsel + b3v;   // zb[i-row][j-col]
        }
    }
    __syncthreads();

    // ---- coalesced stores of both triangle halves ----
    if (t < 256) {
        int r = t >> 4, c = t & 15;
        pred[((size_t)n * SP + iBase + r) * SP + jBase + c] = zb[r * 17 + c];
    } else if (!diag) {
        int tt = t - 256;
        int r = tt >> 4, c = tt & 15;
        pred[((size_t)n * SP + jBase + r) * SP + iBase + c] = zb[c * 17 + r];
    }
}

// Streaming BCE + masked loss reduction (latency-tolerant, full occupancy).
__global__ __launch_bounds__(256) void k_loss(
    const float* __restrict__ pred, const float* __restrict__ heat,
    const float* __restrict__ mask, const float* __restrict__ pos,
    float* __restrict__ accum)
{
    int idx = blockIdx.x * 256 + threadIdx.x;        // vec4 index, 131072 total
    f32x4 z = ((const f32x4*)pred)[idx];
    f32x4 tg = ((const f32x4*)heat)[idx];
    f32x4 mk = ((const f32x4*)mask)[idx];
    f32x4 pm = ((const f32x4*)pos)[idx];
    float num = 0.0f, den = 0.0f;
#pragma unroll
    for (int e = 0; e < 4; ++e) {
        float zz = z[e];
        float bce = fmaxf(zz, 0.0f) - zz * tg[e] + __logf(1.0f + __expf(-fabsf(zz)));
        num += bce * mk[e] * pm[e];
        den += pm[e];
    }
#pragma unroll
    for (int off = 32; off > 0; off >>= 1) {
        num += __shfl_down(num, off, 64);
        den += __shfl_down(den, off, 64);
    }
    __shared__ float rb[8];
    int l = threadIdx.x & 63, w = threadIdx.x >> 6;
    if (l == 0) { rb[w] = num; rb[4 + w] = den; }
    __syncthreads();
    if (threadIdx.x == 0) {
        atomicAdd(&accum[0], (rb[0] + rb[1]) + (rb[2] + rb[3]));
        atomicAdd(&accum[1], (rb[4] + rb[5]) + (rb[6] + rb[7]));
    }
}

__global__ void k_final(const float* __restrict__ accum, float* __restrict__ out)
{
    out[0] = accum[0] / accum[1];
}

extern "C" void kernel_launch(void* const* d_in, const int* in_sizes, int n_in,
                              void* d_out, int out_size, void* d_ws, size_t ws_size,
                              hipStream_t stream)
{
    const float* points = (const float*)d_in[0];
    const float* heat   = (const float*)d_in[1];
    const float* mask   = (const float*)d_in[2];
    const float* pos    = (const float*)d_in[3];
    const float* W0     = (const float*)d_in[4];
    const float* b0     = (const float*)d_in[5];
    const float* W1     = (const float*)d_in[6];
    const float* b1     = (const float*)d_in[7];
    const float* W2     = (const float*)d_in[8];
    const float* b2     = (const float*)d_in[9];
    const float* W3     = (const float*)d_in[10];
    const float* b3     = (const float*)d_in[11];

    float* pred = (float*)d_out;                        // (2,512,512)
    float* loss = pred + (size_t)N_ * SP * SP;          // scalar

    char* ws = (char*)d_ws;
    float* accum = (float*)ws;                          // [0]=num,[1]=den
    float* A     = (float*)(ws + 256);                  // 1024*128 f32 = 512 KiB
    short* W1Th  = (short*)(ws + 256 + 524288);
    short* W1Tl  = (short*)(ws + 256 + 524288 + 16384);
    short* W2Th  = (short*)(ws + 256 + 524288 + 32768);
    short* W2Tl  = (short*)(ws + 256 + 524288 + 36864);

    hipMemsetAsync(d_ws, 0, 256, stream);
    k_prepW<<<8, 256, 0, stream>>>(W1, W2, W1Th, W1Tl, W2Th, W2Tl);
    k_precompA<<<N_ * SP / 4, 512, 0, stream>>>(points, W0, b0, A);
    k_main<<<dim3(528, 1, N_), 512, 0, stream>>>(
        A, W1Th, W1Tl, W2Th, W2Tl, b1, b2, W3, b3, pred);
    k_loss<<<N_ * SP * SP / 4 / 256, 256, 0, stream>>>(pred, heat, mask, pos, accum);
    k_final<<<1, 1, 0, stream>>>(accum, loss);
}

// Round 9
// 90.149 us; speedup vs baseline: 4.3109x; 1.0988x over previous
//
#include <hip/hip_runtime.h>
#include <stdint.h>

#define N_ 2
#define C_ 256
#define SP 512
#define H1 128
#define H2 64
#define H3 32

using f32x4 = __attribute__((ext_vector_type(4))) float;
using s16x8 = __attribute__((ext_vector_type(8))) short;

__device__ __forceinline__ uint32_t f2bf_rne(float x) {
    uint32_t u = __builtin_bit_cast(uint32_t, x);
    return (u + 0x7FFFu + ((u >> 16) & 1u)) >> 16;
}
__device__ __forceinline__ float bf2f(uint32_t h) {
    return __builtin_bit_cast(float, h << 16);
}

// A[row][k] = sum_c points[n][c][i] * W0[c][k] + 0.5*b0[k]; row = n*SP+i.
// 32 threads per row, 4 k-cols each (f32x4), W0 loads coalesced.
__global__ __launch_bounds__(512) void k_precompA(
    const float* __restrict__ points, const float* __restrict__ W0,
    const float* __restrict__ b0, float* __restrict__ A)
{
    int row = blockIdx.x * 16 + (threadIdx.x >> 5);   // 0..1023
    int n = row >> 9, i = row & (SP - 1);
    int k4 = threadIdx.x & 31;                        // k = k4*4
    const float* pb = points + (size_t)n * C_ * SP + i;
    f32x4 p0 = {0.f, 0.f, 0.f, 0.f}, p1 = {0.f, 0.f, 0.f, 0.f};
#pragma unroll 8
    for (int c = 0; c < C_; c += 2) {
        float s0 = pb[(size_t)c * SP];                // wave-uniform -> s_load
        float s1 = pb[(size_t)(c + 1) * SP];
        f32x4 w0 = *(const f32x4*)(W0 + c * H1 + k4 * 4);
        f32x4 w1 = *(const f32x4*)(W0 + (c + 1) * H1 + k4 * 4);
#pragma unroll
        for (int e = 0; e < 4; ++e) {
            p0[e] = fmaf(s0, w0[e], p0[e]);
            p1[e] = fmaf(s1, w1[e], p1[e]);
        }
    }
    f32x4 bb = *(const f32x4*)(b0 + k4 * 4);
    f32x4 out;
#pragma unroll
    for (int e = 0; e < 4; ++e) out[e] = 0.5f * bb[e] + (p0[e] + p1[e]);
    *(f32x4*)(A + (size_t)row * H1 + k4 * 4) = out;
}

// Split W1 (128x64) and W2 (64x32) into transposed bf16 hi/lo: WT[col][k]
__global__ __launch_bounds__(256) void k_prepW(
    const float* __restrict__ W1, const float* __restrict__ W2,
    short* __restrict__ W1Th, short* __restrict__ W1Tl,
    short* __restrict__ W2Th, short* __restrict__ W2Tl)
{
    int t0 = blockIdx.x * 256 + threadIdx.x;
    int stride = gridDim.x * 256;
    for (int idx = t0; idx < H2 * H1; idx += stride) {
        int col = idx >> 7, k = idx & 127;
        float wv = W1[k * H2 + col];
        uint32_t h = f2bf_rne(wv);
        W1Th[idx] = (short)h;
        W1Tl[idx] = (short)f2bf_rne(wv - bf2f(h));
    }
    for (int idx = t0; idx < H3 * H2; idx += stride) {
        int col = idx >> 6, k = idx & 63;
        float wv = W2[k * H3 + col];
        uint32_t h = f2bf_rne(wv);
        W2Th[idx] = (short)h;
        W2Tl[idx] = (short)f2bf_rne(wv - bf2f(h));
    }
}

// Tile = 32 i-rows x 16 j-cols. 8 waves; wave w owns i-rows {iBase+4w+m}, m=0..3
// (amortizes each B-fragment load over 4 MFMAs -> W traffic per output halved
// vs R8). Triangular tile grid: 272 tiles/batch; per-pixel guards j>=i (primary)
// / j>i (mirror) handle diagonal straddlers. BCE+loss fused (coalesced loads).
// Launch-bounds history: (512,8)->32reg spill; (512,4)->64reg spill; keep (512,2).
__global__ __launch_bounds__(512, 2) void k_main(
    const float* __restrict__ A,
    const short* __restrict__ W1Th, const short* __restrict__ W1Tl,
    const short* __restrict__ W2Th, const short* __restrict__ W2Tl,
    const float* __restrict__ b1, const float* __restrict__ b2,
    const float* __restrict__ W3, const float* __restrict__ b3,
    const float* __restrict__ heat, const float* __restrict__ mask,
    const float* __restrict__ pos,
    float* __restrict__ pred, float* __restrict__ accum)
{
    // unrank u in [0,272): ci = i-chunk (32 rows), cj = j-chunk (16 cols),
    // launched set: cj >= 2*ci ; start(ci) = ci*(33-ci)
    int u = blockIdx.x;
    int ci = (int)((33.0f - sqrtf(1089.0f - 4.0f * (float)u)) * 0.5f);
    int start = ci * (33 - ci);
    while (start > u) { --ci; start = ci * (33 - ci); }
    while (u - start >= 32 - 2 * ci) { ++ci; start = ci * (33 - ci); }
    int cj = 2 * ci + (u - start);
    int n = blockIdx.z;
    int iBase = ci * 32, jBase = cj * 16;

    // LDS: per-wave X2 [32][64] bf16 swz (4KB) x8 ; zb[32][17] f32 ; red
    __shared__ __align__(16) char smem[8 * 4096 + 32 * 17 * 4 + 64];
    float* zb = (float*)(smem + 8 * 4096);
    float* rb = (float*)(smem + 8 * 4096 + 32 * 17 * 4);

    int t = threadIdx.x;
    int l = t & 63, w = t >> 6;
    int lc = l & 15, kg = l >> 4;

    const float* Abase = A + (size_t)n * SP * H1;
    const float* Aj_row = Abase + (size_t)(jBase + lc) * H1;   // j-pixel per lane
    char* myx2 = smem + w * 4096;

    // ---- layer 2: C1[m] = relu(Ai_m + Aj) @ W1 + b1 (3-product split bf16) ----
    f32x4 acc[4][4];
#pragma unroll
    for (int cf = 0; cf < 4; ++cf) {
        float bv = b1[cf * 16 + lc];
#pragma unroll
        for (int m = 0; m < 4; ++m) acc[m][cf] = (f32x4){bv, bv, bv, bv};
    }
#pragma unroll
    for (int ks = 0; ks < 4; ++ks) {
        const float* aj_p = Aj_row + ks * 32 + kg * 8;
        f32x4 aj0 = *(const f32x4*)(aj_p);
        f32x4 aj1 = *(const f32x4*)(aj_p + 4);
        s16x8 ahi[4], alo[4];
#pragma unroll
        for (int m = 0; m < 4; ++m) {
            const float* ai_p = Abase + (size_t)(iBase + 4 * w + m) * H1 + ks * 32 + kg * 8;
            f32x4 ai0 = *(const f32x4*)(ai_p);
            f32x4 ai1 = *(const f32x4*)(ai_p + 4);
#pragma unroll
            for (int e = 0; e < 8; ++e) {
                float s = (e < 4 ? ai0[e] : ai1[e - 4]) + (e < 4 ? aj0[e] : aj1[e - 4]);
                float x = fmaxf(s, 0.0f);
                uint32_t hb = __builtin_bit_cast(uint32_t, x) & 0xFFFF0000u;
                float lof = x - __builtin_bit_cast(float, hb);
                ahi[m][e] = (short)(hb >> 16);
                alo[m][e] = (short)(__builtin_bit_cast(uint32_t, lof) >> 16);
            }
        }
#pragma unroll
        for (int cf = 0; cf < 4; ++cf) {
            int boff = (cf * 16 + lc) * H1 + ks * 32 + kg * 8;
            s16x8 bhi = *(const s16x8*)(W1Th + boff);
            s16x8 blo = *(const s16x8*)(W1Tl + boff);
#pragma unroll
            for (int m = 0; m < 4; ++m) {
                acc[m][cf] = __builtin_amdgcn_mfma_f32_16x16x32_bf16(alo[m], bhi, acc[m][cf], 0, 0, 0);
                acc[m][cf] = __builtin_amdgcn_mfma_f32_16x16x32_bf16(ahi[m], blo, acc[m][cf], 0, 0, 0);
                acc[m][cf] = __builtin_amdgcn_mfma_f32_16x16x32_bf16(ahi[m], bhi, acc[m][cf], 0, 0, 0);
            }
        }
    }

    // ---- layers 3+4 in two m-halves (reuse 4KB/wave X2 LDS, same-wave only) ----
    float w3a = W3[lc], w3b = W3[16 + lc];
    float b3v = b3[0];
#pragma unroll
    for (int half = 0; half < 2; ++half) {
        // X2 rows for m = 2*half + mh  -> lds row = mh*16 + jpix
#pragma unroll
        for (int mh = 0; mh < 2; ++mh) {
            int m = 2 * half + mh;
#pragma unroll
            for (int cf = 0; cf < 4; ++cf)
#pragma unroll
                for (int r = 0; r < 4; ++r) {
                    int row = mh * 16 + kg * 4 + r;
                    int col = cf * 16 + lc;
                    int g = col >> 3;
                    int off = row * 128 + ((g ^ (row & 7)) << 4) + (col & 7) * 2;
                    *(short*)(myx2 + off) = (short)f2bf_rne(fmaxf(acc[m][cf][r], 0.0f));
                }
        }
        // layer 3: C2[mh] = X2[mh] @ (W2hi + W2lo) + b2
        f32x4 acc2[2][2];
#pragma unroll
        for (int cf = 0; cf < 2; ++cf) {
            float bv = b2[cf * 16 + lc];
            acc2[0][cf] = (f32x4){bv, bv, bv, bv};
            acc2[1][cf] = (f32x4){bv, bv, bv, bv};
        }
#pragma unroll
        for (int ks = 0; ks < 2; ++ks) {
#pragma unroll
            for (int mh = 0; mh < 2; ++mh) {
                int row = mh * 16 + lc;
                int g = ks * 4 + kg;
                int off = row * 128 + ((g ^ (row & 7)) << 4);
                s16x8 xbf = *(const s16x8*)(myx2 + off);
#pragma unroll
                for (int cf = 0; cf < 2; ++cf) {
                    int boff = (cf * 16 + lc) * H2 + ks * 32 + kg * 8;
                    s16x8 bhi = *(const s16x8*)(W2Th + boff);
                    s16x8 blo = *(const s16x8*)(W2Tl + boff);
                    acc2[mh][cf] = __builtin_amdgcn_mfma_f32_16x16x32_bf16(xbf, blo, acc2[mh][cf], 0, 0, 0);
                    acc2[mh][cf] = __builtin_amdgcn_mfma_f32_16x16x32_bf16(xbf, bhi, acc2[mh][cf], 0, 0, 0);
                }
            }
        }
        // layer 4: z = relu(a3).W3 + b3 -> zb tile
#pragma unroll
        for (int mh = 0; mh < 2; ++mh) {
            int m = 2 * half + mh;
            float zr0 = fmaxf(acc2[mh][0][0], 0.0f) * w3a + fmaxf(acc2[mh][1][0], 0.0f) * w3b;
            float zr1 = fmaxf(acc2[mh][0][1], 0.0f) * w3a + fmaxf(acc2[mh][1][1], 0.0f) * w3b;
            float zr2 = fmaxf(acc2[mh][0][2], 0.0f) * w3a + fmaxf(acc2[mh][1][2], 0.0f) * w3b;
            float zr3 = fmaxf(acc2[mh][0][3], 0.0f) * w3a + fmaxf(acc2[mh][1][3], 0.0f) * w3b;
#pragma unroll
            for (int off = 1; off < 16; off <<= 1) {     // sum hidden cols (lc)
                zr0 += __shfl_xor(zr0, off, 64);
                zr1 += __shfl_xor(zr1, off, 64);
                zr2 += __shfl_xor(zr2, off, 64);
                zr3 += __shfl_xor(zr3, off, 64);
            }
            float zsel = zr0;
            zsel = (lc == 1) ? zr1 : zsel;
            zsel = (lc == 2) ? zr2 : zsel;
            zsel = (lc == 3) ? zr3 : zsel;
            if (lc < 4) {
                int jpix = kg * 4 + lc;
                zb[(4 * w + m) * 17 + jpix] = zsel + b3v;
            }
        }
    }
    __syncthreads();

    // ---- coalesced stores + fused BCE/loss (guards make straddlers exact) ----
    float num = 0.0f, den = 0.0f;
    {
        // primary: 32 rows x 16 cols, guard j >= i
        int r = t >> 4, c = t & 15;
        int i = iBase + r, j = jBase + c;
        if (j >= i) {
            float z = zb[r * 17 + c];
            size_t idx = ((size_t)n * SP + i) * SP + j;
            pred[idx] = z;
            float tg = heat[idx], mk = mask[idx], pm = pos[idx];
            float bce = fmaxf(z, 0.0f) - z * tg + __logf(1.0f + __expf(-fabsf(z)));
            num += bce * mk * pm;
            den += pm;
        }
        // mirror: 16 rows x 32 cols at (jBase+mr, iBase+mc), guard J > I
        int mr = t >> 5, mc = t & 31;
        int J = jBase + mr, I = iBase + mc;
        if (J > I) {
            float z = zb[mc * 17 + mr];
            size_t idx = ((size_t)n * SP + J) * SP + I;
            pred[idx] = z;
            float tg = heat[idx], mk = mask[idx], pm = pos[idx];
            float bce = fmaxf(z, 0.0f) - z * tg + __logf(1.0f + __expf(-fabsf(z)));
            num += bce * mk * pm;
            den += pm;
        }
    }
#pragma unroll
    for (int off = 32; off > 0; off >>= 1) {
        num += __shfl_down(num, off, 64);
        den += __shfl_down(den, off, 64);
    }
    if (l == 0) { rb[w] = num; rb[8 + w] = den; }
    __syncthreads();
    if (t == 0) {
        float sn = 0.0f, sd = 0.0f;
#pragma unroll
        for (int q = 0; q < 8; ++q) { sn += rb[q]; sd += rb[8 + q]; }
        atomicAdd(&accum[0], sn);
        atomicAdd(&accum[1], sd);
    }
}

__global__ void k_final(const float* __restrict__ accum, float* __restrict__ out)
{
    out[0] = accum[0] / accum[1];
}

extern "C" void kernel_launch(void* const* d_in, const int* in_sizes, int n_in,
                              void* d_out, int out_size, void* d_ws, size_t ws_size,
                              hipStream_t stream)
{
    const float* points = (const float*)d_in[0];
    const float* heat   = (const float*)d_in[1];
    const float* mask   = (const float*)d_in[2];
    const float* pos    = (const float*)d_in[3];
    const float* W0     = (const float*)d_in[4];
    const float* b0     = (const float*)d_in[5];
    const float* W1     = (const float*)d_in[6];
    const float* b1     = (const float*)d_in[7];
    const float* W2     = (const float*)d_in[8];
    const float* b2     = (const float*)d_in[9];
    const float* W3     = (const float*)d_in[10];
    const float* b3     = (const float*)d_in[11];

    float* pred = (float*)d_out;                        // (2,512,512)
    float* loss = pred + (size_t)N_ * SP * SP;          // scalar

    char* ws = (char*)d_ws;
    float* accum = (float*)ws;                          // [0]=num,[1]=den
    float* A     = (float*)(ws + 256);                  // 1024*128 f32 = 512 KiB
    short* W1Th  = (short*)(ws + 256 + 524288);
    short* W1Tl  = (short*)(ws + 256 + 524288 + 16384);
    short* W2Th  = (short*)(ws + 256 + 524288 + 32768);
    short* W2Tl  = (short*)(ws + 256 + 524288 + 36864);

    hipMemsetAsync(d_ws, 0, 256, stream);
    k_prepW<<<8, 256, 0, stream>>>(W1, W2, W1Th, W1Tl, W2Th, W2Tl);
    k_precompA<<<64, 512, 0, stream>>>(points, W0, b0, A);
    k_main<<<dim3(272, 1, N_), 512, 0, stream>>>(
        A, W1Th, W1Tl, W2Th, W2Tl, b1, b2, W3, b3, heat, mask, pos, pred, accum);
    k_final<<<1, 1, 0, stream>>>(accum, loss);
}

// Round 10
// 60.639 us; speedup vs baseline: 6.4089x; 1.4867x over previous
//
#include <hip/hip_runtime.h>
#include <stdint.h>

#define N_ 2
#define C_ 256
#define SP 512
#define H1 128
#define H2 64
#define H3 32

using f32x4 = __attribute__((ext_vector_type(4))) float;
using s16x8 = __attribute__((ext_vector_type(8))) short;

__device__ __forceinline__ uint32_t f2bf_rne(float x) {
    uint32_t u = __builtin_bit_cast(uint32_t, x);
    return (u + 0x7FFFu + ((u >> 16) & 1u)) >> 16;
}
__device__ __forceinline__ float bf2f(uint32_t h) {
    return __builtin_bit_cast(float, h << 16);
}

// A[row][k] = sum_c points[n][c][i] * W0[c][k] + 0.5*b0[k]; row = n*SP+i.
// c-split x4: team = (rloc 0..3, cq 0..3); each c-quarter of W0 (32KB) is
// L1-resident and shared by the 4 row-teams on the same cq -> latency-friendly.
__global__ __launch_bounds__(512) void k_precompA(
    const float* __restrict__ points, const float* __restrict__ W0,
    const float* __restrict__ b0, float* __restrict__ A)
{
    int t = threadIdx.x;
    int k4 = t & 31;                  // 4 k-cols per thread
    int team = t >> 5;                // 0..15
    int rloc = team & 3, cq = team >> 2;
    int row = blockIdx.x * 4 + rloc;  // grid = 256 blocks
    int n = row >> 9, i = row & (SP - 1);
    const float* pb = points + (size_t)n * C_ * SP + i;
    f32x4 p0 = {0.f, 0.f, 0.f, 0.f}, p1 = {0.f, 0.f, 0.f, 0.f};
    int c0 = cq * 64;
#pragma unroll 8
    for (int c = c0; c < c0 + 64; c += 2) {
        float s0 = pb[(size_t)c * SP];
        float s1 = pb[(size_t)(c + 1) * SP];
        f32x4 w0v = *(const f32x4*)(W0 + c * H1 + k4 * 4);
        f32x4 w1v = *(const f32x4*)(W0 + (c + 1) * H1 + k4 * 4);
#pragma unroll
        for (int e = 0; e < 4; ++e) {
            p0[e] = fmaf(s0, w0v[e], p0[e]);
            p1[e] = fmaf(s1, w1v[e], p1[e]);
        }
    }
#pragma unroll
    for (int e = 0; e < 4; ++e) p0[e] += p1[e];
    __shared__ f32x4 part[16][32];    // 8 KB
    part[team][k4] = p0;
    __syncthreads();
    int r2 = t >> 7, kk = t & 127;    // 4 rows x 128 cols
    float s = 0.5f * b0[kk]
            + part[r2][kk >> 2][kk & 3] + part[r2 + 4][kk >> 2][kk & 3]
            + part[r2 + 8][kk >> 2][kk & 3] + part[r2 + 12][kk >> 2][kk & 3];
    A[(size_t)(blockIdx.x * 4 + r2) * H1 + kk] = s;
}

// Split W1 (128x64) / W2 (64x32) into transposed bf16 hi/lo, PRE-SWIZZLED for
// conflict-free ds_read_b128 in k_main:
//   W1T element (col,k) -> col*128 + (((k>>3) ^ (col&15))<<3 | (k&7))
//   W2T element (col,k) -> col*64  + (((k>>3) ^ (col&7 ))<<3 | (k&7))
__global__ __launch_bounds__(256) void k_prepW(
    const float* __restrict__ W1, const float* __restrict__ W2,
    short* __restrict__ W1Th, short* __restrict__ W1Tl,
    short* __restrict__ W2Th, short* __restrict__ W2Tl)
{
    int t0 = blockIdx.x * 256 + threadIdx.x;
    int stride = gridDim.x * 256;
    for (int idx = t0; idx < H2 * H1; idx += stride) {
        int col = idx >> 7, k = idx & 127;
        float wv = W1[k * H2 + col];
        uint32_t h = f2bf_rne(wv);
        int sidx = col * 128 + ((((k >> 3) ^ (col & 15)) << 3) | (k & 7));
        W1Th[sidx] = (short)h;
        W1Tl[sidx] = (short)f2bf_rne(wv - bf2f(h));
    }
    for (int idx = t0; idx < H3 * H2; idx += stride) {
        int col = idx >> 6, k = idx & 63;
        float wv = W2[k * H3 + col];
        uint32_t h = f2bf_rne(wv);
        int sidx = col * 64 + ((((k >> 3) ^ (col & 7)) << 3) | (k & 7));
        W2Th[sidx] = (short)h;
        W2Tl[sidx] = (short)f2bf_rne(wv - bf2f(h));
    }
}

// Tile = 32 i-rows x 16 j-cols, 8 waves, wave owns 4 interleaved i-rows.
// NEW (R10): all W tables staged in LDS once per block (40KB, swizzled) -- kills
// the per-wave 40KB global W re-read (L1 thrash + serialized L2 latency).
// Launch-bounds history: (512,8)->32reg spill; (512,4)->64reg spill; keep (512,2).
__global__ __launch_bounds__(512, 2) void k_main(
    const float* __restrict__ A,
    const short* __restrict__ wtab,     // W1Th|W1Tl|W2Th|W2Tl contiguous, 40960B
    const float* __restrict__ b1, const float* __restrict__ b2,
    const float* __restrict__ W3, const float* __restrict__ b3,
    const float* __restrict__ heat, const float* __restrict__ mask,
    const float* __restrict__ pos,
    float* __restrict__ pred, float* __restrict__ accum)
{
    // unrank u in [0,272): ci (32-row chunk), cj (16-col chunk), cj >= 2*ci
    int u = blockIdx.x;
    int ci = (int)((33.0f - sqrtf(1089.0f - 4.0f * (float)u)) * 0.5f);
    int start = ci * (33 - ci);
    while (start > u) { --ci; start = ci * (33 - ci); }
    while (u - start >= 32 - 2 * ci) { ++ci; start = ci * (33 - ci); }
    int cj = 2 * ci + (u - start);
    int n = blockIdx.z;
    int iBase = ci * 32, jBase = cj * 16;

    // LDS: W tables 40960 | X2 8x4096 | zb 32x17 f32 | red
    __shared__ __align__(16) char smem[40960 + 32768 + 32 * 17 * 4 + 64];
    int t = threadIdx.x;

    // ---- stage W into LDS (coalesced, 80B/thread) ----
    {
        const f32x4* src = (const f32x4*)wtab;
        f32x4* dst = (f32x4*)smem;
#pragma unroll
        for (int q = 0; q < 5; ++q)
            dst[t + q * 512] = src[t + q * 512];
    }
    __syncthreads();

    const short* lw1h = (const short*)smem;      // 8192 shorts
    const short* lw1l = lw1h + 8192;
    const short* lw2h = lw1l + 8192;             // 2048 shorts
    const short* lw2l = lw2h + 2048;
    char* x2base = smem + 40960;
    float* zb = (float*)(smem + 40960 + 32768);
    float* rb = (float*)(smem + 40960 + 32768 + 32 * 17 * 4);

    int l = t & 63, w = t >> 6;
    int lc = l & 15, kg = l >> 4;

    const float* Abase = A + (size_t)n * SP * H1;
    const float* Aj_row = Abase + (size_t)(jBase + lc) * H1;   // j-pixel per lane
    char* myx2 = x2base + w * 4096;

    // ---- layer 2: C1[m] = relu(Ai_m + Aj) @ W1 + b1 (3-product split bf16) ----
    f32x4 acc[4][4];
#pragma unroll
    for (int cf = 0; cf < 4; ++cf) {
        float bv = b1[cf * 16 + lc];
#pragma unroll
        for (int m = 0; m < 4; ++m) acc[m][cf] = (f32x4){bv, bv, bv, bv};
    }
#pragma unroll
    for (int ks = 0; ks < 4; ++ks) {
        const float* aj_p = Aj_row + ks * 32 + kg * 8;
        f32x4 aj0 = *(const f32x4*)(aj_p);
        f32x4 aj1 = *(const f32x4*)(aj_p + 4);
        s16x8 ahi[4], alo[4];
#pragma unroll
        for (int m = 0; m < 4; ++m) {
            const float* ai_p = Abase + (size_t)(iBase + 4 * w + m) * H1 + ks * 32 + kg * 8;
            f32x4 ai0 = *(const f32x4*)(ai_p);
            f32x4 ai1 = *(const f32x4*)(ai_p + 4);
#pragma unroll
            for (int e = 0; e < 8; ++e) {
                float s = (e < 4 ? ai0[e] : ai1[e - 4]) + (e < 4 ? aj0[e] : aj1[e - 4]);
                float x = fmaxf(s, 0.0f);
                uint32_t hb = __builtin_bit_cast(uint32_t, x) & 0xFFFF0000u;
                float lof = x - __builtin_bit_cast(float, hb);
                ahi[m][e] = (short)(hb >> 16);
                alo[m][e] = (short)(__builtin_bit_cast(uint32_t, lof) >> 16);
            }
        }
#pragma unroll
        for (int cf = 0; cf < 4; ++cf) {
            int colb = cf * 16 + lc;
            int boff = colb * 128 + ((((ks * 4 + kg) ^ lc)) << 3);   // swizzled
            s16x8 bhi = *(const s16x8*)(lw1h + boff);
            s16x8 blo = *(const s16x8*)(lw1l + boff);
#pragma unroll
            for (int m = 0; m < 4; ++m) {
                acc[m][cf] = __builtin_amdgcn_mfma_f32_16x16x32_bf16(alo[m], bhi, acc[m][cf], 0, 0, 0);
                acc[m][cf] = __builtin_amdgcn_mfma_f32_16x16x32_bf16(ahi[m], blo, acc[m][cf], 0, 0, 0);
                acc[m][cf] = __builtin_amdgcn_mfma_f32_16x16x32_bf16(ahi[m], bhi, acc[m][cf], 0, 0, 0);
            }
        }
    }

    // ---- layers 3+4 in two m-halves (reuse 4KB/wave X2 LDS, same-wave only) ----
    float w3a = W3[lc], w3b = W3[16 + lc];
    float b3v = b3[0];
#pragma unroll
    for (int half = 0; half < 2; ++half) {
#pragma unroll
        for (int mh = 0; mh < 2; ++mh) {
            int m = 2 * half + mh;
#pragma unroll
            for (int cf = 0; cf < 4; ++cf)
#pragma unroll
                for (int r = 0; r < 4; ++r) {
                    int row = mh * 16 + kg * 4 + r;
                    int col = cf * 16 + lc;
                    int g = col >> 3;
                    int off = row * 128 + ((g ^ (row & 7)) << 4) + (col & 7) * 2;
                    *(short*)(myx2 + off) = (short)f2bf_rne(fmaxf(acc[m][cf][r], 0.0f));
                }
        }
        f32x4 acc2[2][2];
#pragma unroll
        for (int cf = 0; cf < 2; ++cf) {
            float bv = b2[cf * 16 + lc];
            acc2[0][cf] = (f32x4){bv, bv, bv, bv};
            acc2[1][cf] = (f32x4){bv, bv, bv, bv};
        }
#pragma unroll
        for (int ks = 0; ks < 2; ++ks) {
#pragma unroll
            for (int mh = 0; mh < 2; ++mh) {
                int row = mh * 16 + lc;
                int g = ks * 4 + kg;
                int off = row * 128 + ((g ^ (row & 7)) << 4);
                s16x8 xbf = *(const s16x8*)(myx2 + off);
#pragma unroll
                for (int cf = 0; cf < 2; ++cf) {
                    int colb = cf * 16 + lc;
                    int boff = colb * 64 + ((((ks * 4 + kg) ^ (lc & 7))) << 3);  // swizzled
                    s16x8 bhi = *(const s16x8*)(lw2h + boff);
                    s16x8 blo = *(const s16x8*)(lw2l + boff);
                    acc2[mh][cf] = __builtin_amdgcn_mfma_f32_16x16x32_bf16(xbf, blo, acc2[mh][cf], 0, 0, 0);
                    acc2[mh][cf] = __builtin_amdgcn_mfma_f32_16x16x32_bf16(xbf, bhi, acc2[mh][cf], 0, 0, 0);
                }
            }
        }
#pragma unroll
        for (int mh = 0; mh < 2; ++mh) {
            int m = 2 * half + mh;
            float zr0 = fmaxf(acc2[mh][0][0], 0.0f) * w3a + fmaxf(acc2[mh][1][0], 0.0f) * w3b;
            float zr1 = fmaxf(acc2[mh][0][1], 0.0f) * w3a + fmaxf(acc2[mh][1][1], 0.0f) * w3b;
            float zr2 = fmaxf(acc2[mh][0][2], 0.0f) * w3a + fmaxf(acc2[mh][1][2], 0.0f) * w3b;
            float zr3 = fmaxf(acc2[mh][0][3], 0.0f) * w3a + fmaxf(acc2[mh][1][3], 0.0f) * w3b;
#pragma unroll
            for (int off = 1; off < 16; off <<= 1) {     // sum hidden cols (lc)
                zr0 += __shfl_xor(zr0, off, 64);
                zr1 += __shfl_xor(zr1, off, 64);
                zr2 += __shfl_xor(zr2, off, 64);
                zr3 += __shfl_xor(zr3, off, 64);
            }
            float zsel = zr0;
            zsel = (lc == 1) ? zr1 : zsel;
            zsel = (lc == 2) ? zr2 : zsel;
            zsel = (lc == 3) ? zr3 : zsel;
            if (lc < 4) {
                int jpix = kg * 4 + lc;
                zb[(4 * w + m) * 17 + jpix] = zsel + b3v;
            }
        }
    }
    __syncthreads();

    // ---- coalesced stores + fused BCE/loss (guards handle straddlers) ----
    float num = 0.0f, den = 0.0f;
    {
        int r = t >> 4, c = t & 15;                  // primary 32x16, j >= i
        int i = iBase + r, j = jBase + c;
        if (j >= i) {
            float z = zb[r * 17 + c];
            size_t idx = ((size_t)n * SP + i) * SP + j;
            pred[idx] = z;
            float tg = heat[idx], mk = mask[idx], pm = pos[idx];
            float bce = fmaxf(z, 0.0f) - z * tg + __logf(1.0f + __expf(-fabsf(z)));
            num += bce * mk * pm;
            den += pm;
        }
        int mr = t >> 5, mc = t & 31;                // mirror 16x32, J > I
        int J = jBase + mr, I = iBase + mc;
        if (J > I) {
            float z = zb[mc * 17 + mr];
            size_t idx = ((size_t)n * SP + J) * SP + I;
            pred[idx] = z;
            float tg = heat[idx], mk = mask[idx], pm = pos[idx];
            float bce = fmaxf(z, 0.0f) - z * tg + __logf(1.0f + __expf(-fabsf(z)));
            num += bce * mk * pm;
            den += pm;
        }
    }
#pragma unroll
    for (int off = 32; off > 0; off >>= 1) {
        num += __shfl_down(num, off, 64);
        den += __shfl_down(den, off, 64);
    }
    if (l == 0) { rb[w] = num; rb[8 + w] = den; }
    __syncthreads();
    if (t == 0) {
        float sn = 0.0f, sd = 0.0f;
#pragma unroll
        for (int q = 0; q < 8; ++q) { sn += rb[q]; sd += rb[8 + q]; }
        atomicAdd(&accum[0], sn);
        atomicAdd(&accum[1], sd);
    }
}

__global__ void k_final(const float* __restrict__ accum, float* __restrict__ out)
{
    out[0] = accum[0] / accum[1];
}

extern "C" void kernel_launch(void* const* d_in, const int* in_sizes, int n_in,
                              void* d_out, int out_size, void* d_ws, size_t ws_size,
                              hipStream_t stream)
{
    const float* points = (const float*)d_in[0];
    const float* heat   = (const float*)d_in[1];
    const float* mask   = (const float*)d_in[2];
    const float* pos    = (const float*)d_in[3];
    const float* W0     = (const float*)d_in[4];
    const float* b0     = (const float*)d_in[5];
    const float* W1     = (const float*)d_in[6];
    const float* b1     = (const float*)d_in[7];
    const float* W2     = (const float*)d_in[8];
    const float* b2     = (const float*)d_in[9];
    const float* W3     = (const float*)d_in[10];
    const float* b3     = (const float*)d_in[11];

    float* pred = (float*)d_out;                        // (2,512,512)
    float* loss = pred + (size_t)N_ * SP * SP;          // scalar

    char* ws = (char*)d_ws;
    float* accum = (float*)ws;                          // [0]=num,[1]=den
    float* A     = (float*)(ws + 256);                  // 1024*128 f32 = 512 KiB
    short* W1Th  = (short*)(ws + 256 + 524288);         // contiguous 40960B:
    short* W1Tl  = (short*)(ws + 256 + 524288 + 16384); //   W1Th|W1Tl|W2Th|W2Tl
    short* W2Th  = (short*)(ws + 256 + 524288 + 32768);
    short* W2Tl  = (short*)(ws + 256 + 524288 + 36864);

    hipMemsetAsync(d_ws, 0, 256, stream);
    k_prepW<<<8, 256, 0, stream>>>(W1, W2, W1Th, W1Tl, W2Th, W2Tl);
    k_precompA<<<256, 512, 0, stream>>>(points, W0, b0, A);
    k_main<<<dim3(272, 1, N_), 512, 0, stream>>>(
        A, W1Th, b1, b2, W3, b3, heat, mask, pos, pred, accum);
    k_final<<<1, 1, 0, stream>>>(accum, loss);
}

// Round 11
// 59.947 us; speedup vs baseline: 6.4829x; 1.0115x over previous
//
#include <hip/hip_runtime.h>
#include <stdint.h>

#define N_ 2
#define C_ 256
#define SP 512
#define H1 128
#define H2 64
#define H3 32

using f32x4 = __attribute__((ext_vector_type(4))) float;
using u32x4 = __attribute__((ext_vector_type(4))) unsigned int;
using s16x8 = __attribute__((ext_vector_type(8))) short;

__device__ __forceinline__ uint32_t f2bf_rne(float x) {
    uint32_t u = __builtin_bit_cast(uint32_t, x);
    return (u + 0x7FFFu + ((u >> 16) & 1u)) >> 16;
}
__device__ __forceinline__ float bf2f(uint32_t h) {
    return __builtin_bit_cast(float, h << 16);
}
__device__ __forceinline__ uint32_t pack_hi2(uint32_t u0, uint32_t u1) {
#if __has_builtin(__builtin_amdgcn_perm)
    return __builtin_amdgcn_perm(u1, u0, 0x07060302u);   // {u1.hi, u0.hi}
#else
    return (u0 >> 16) | (u1 & 0xFFFF0000u);
#endif
}

// A[row][k] = sum_c points[n][c][i]*W0[c][k] + 0.5*b0[k]; row = n*SP+i.
// c-split x4 teams; FUSED: also produces the swizzled bf16 W tables (grid-strided).
__global__ __launch_bounds__(512) void k_precompA(
    const float* __restrict__ points, const float* __restrict__ W0,
    const float* __restrict__ b0,
    const float* __restrict__ W1, const float* __restrict__ W2,
    float* __restrict__ A,
    short* __restrict__ W1Th, short* __restrict__ W2Th, short* __restrict__ W2Tl)
{
    int t = threadIdx.x;
    int k4 = t & 31;
    int team = t >> 5;
    int rloc = team & 3, cq = team >> 2;
    int row = blockIdx.x * 4 + rloc;
    int n = row >> 9, i = row & (SP - 1);
    const float* pb = points + (size_t)n * C_ * SP + i;
    f32x4 p0 = {0.f, 0.f, 0.f, 0.f}, p1 = {0.f, 0.f, 0.f, 0.f};
    int c0 = cq * 64;
#pragma unroll 8
    for (int c = c0; c < c0 + 64; c += 2) {
        float s0 = pb[(size_t)c * SP];
        float s1 = pb[(size_t)(c + 1) * SP];
        f32x4 w0v = *(const f32x4*)(W0 + c * H1 + k4 * 4);
        f32x4 w1v = *(const f32x4*)(W0 + (c + 1) * H1 + k4 * 4);
#pragma unroll
        for (int e = 0; e < 4; ++e) {
            p0[e] = fmaf(s0, w0v[e], p0[e]);
            p1[e] = fmaf(s1, w1v[e], p1[e]);
        }
    }
#pragma unroll
    for (int e = 0; e < 4; ++e) p0[e] += p1[e];
    __shared__ f32x4 part[16][32];
    part[team][k4] = p0;
    __syncthreads();
    int r2 = t >> 7, kk = t & 127;
    float s = 0.5f * b0[kk]
            + part[r2][kk >> 2][kk & 3] + part[r2 + 4][kk >> 2][kk & 3]
            + part[r2 + 8][kk >> 2][kk & 3] + part[r2 + 12][kk >> 2][kk & 3];
    A[(size_t)(blockIdx.x * 4 + r2) * H1 + kk] = s;

    // ---- fused W-prep (swizzled for conflict-free ds_read_b128) ----
    int gid = blockIdx.x * 512 + t;
    int gstride = gridDim.x * 512;
    for (int idx = gid; idx < H2 * H1; idx += gstride) {      // W1 hi (rne) only
        int col = idx >> 7, k = idx & 127;
        int sidx = col * 128 + ((((k >> 3) ^ (col & 15)) << 3) | (k & 7));
        W1Th[sidx] = (short)f2bf_rne(W1[k * H2 + col]);
    }
    for (int idx = gid; idx < H3 * H2; idx += gstride) {      // W2 hi+lo
        int col = idx >> 6, k = idx & 63;
        float wv = W2[k * H3 + col];
        uint32_t h = f2bf_rne(wv);
        int sidx = col * 64 + ((((k >> 3) ^ (col & 7)) << 3) | (k & 7));
        W2Th[sidx] = (short)h;
        W2Tl[sidx] = (short)f2bf_rne(wv - bf2f(h));
    }
}

// Triangular grid u in [0,528): bi<=bj over 32 chunks of 16. Tile 16i x 16j,
// 8 waves, wave w owns i-rows {iBase+2w, iBase+2w+1}. Layer2 = 2-product
// (Ahi+Alo)xW1hi; layer3 = X2bf16 x (W2hi+W2lo); layer4 = MFMA with broadcast
// W3 B-frag (no shfl chains). W tables + per-wave X2/X3 in LDS (50.3KB ->
// 3 blocks/CU). Launch-bounds history: (512,8)->32reg spill; (512,4)->64reg
// spill; (512,2) ok at 72; (512,3) cap 85 targets 24 waves/CU.
__global__ __launch_bounds__(512, 3) void k_main(
    const float* __restrict__ A,
    const short* __restrict__ wtab,     // W1Th(16384B)|W2Th(4096B)|W2Tl(4096B)
    const float* __restrict__ b1, const float* __restrict__ b2,
    const float* __restrict__ W3, const float* __restrict__ b3,
    const float* __restrict__ heat, const float* __restrict__ mask,
    const float* __restrict__ pos,
    float* __restrict__ pred, float* __restrict__ accum)
{
    int u = blockIdx.x;
    int bi = (int)((65.0f - sqrtf(4225.0f - 8.0f * (float)u)) * 0.5f);
    int start = bi * (65 - bi) / 2;
    while (start > u) { --bi; start = bi * (65 - bi) / 2; }
    while (u - start >= 32 - bi) { ++bi; start = bi * (65 - bi) / 2; }
    int bj = bi + (u - start);
    int n = blockIdx.z;
    int iBase = bi * 16, jBase = bj * 16;

    // LDS: wtab 24576 | X2 8x2048 | X3 8x1024 | zb 16x17 f32 | red
    __shared__ __align__(16) char smem[24576 + 16384 + 8192 + 1088 + 64];
    int t = threadIdx.x;

    {   // stage W tables (1536 f32x4 total, 3/thread, coalesced)
        const f32x4* src = (const f32x4*)wtab;
        f32x4* dst = (f32x4*)smem;
#pragma unroll
        for (int q = 0; q < 3; ++q)
            dst[t + q * 512] = src[t + q * 512];
    }
    __syncthreads();

    const short* lw1h = (const short*)smem;          // 8192 shorts
    const short* lw2h = lw1h + 8192;                 // 2048
    const short* lw2l = lw2h + 2048;                 // 2048
    int l = t & 63, w = t >> 6;
    int lc = l & 15, kg = l >> 4;
    char* x2 = smem + 24576 + w * 2048;              // [16][128B] swz
    char* x3 = smem + 24576 + 16384 + w * 1024;      // [16][64B] swz
    float* zb = (float*)(smem + 24576 + 16384 + 8192);
    float* rb = (float*)(smem + 24576 + 16384 + 8192 + 1088);

    const float* Abase = A + (size_t)n * SP * H1;
    const float* Aj_row = Abase + (size_t)(jBase + lc) * H1;
    const float* Ai0 = Abase + (size_t)(iBase + 2 * w) * H1;
    const float* Ai1 = Ai0 + H1;

    // W3 broadcast B-frag (bf16 rne) + b3
    s16x8 bw3;
    {
        f32x4 wa = *(const f32x4*)(W3 + kg * 8);
        f32x4 wb = *(const f32x4*)(W3 + kg * 8 + 4);
        u32x4 wp;
#pragma unroll
        for (int p = 0; p < 2; ++p) {
            wp[p]     = f2bf_rne(wa[2 * p]) | (f2bf_rne(wa[2 * p + 1]) << 16);
            wp[2 + p] = f2bf_rne(wb[2 * p]) | (f2bf_rne(wb[2 * p + 1]) << 16);
        }
        bw3 = __builtin_bit_cast(s16x8, wp);
    }
    float b3v = b3[0];

    // ---- layer 2: acc[m][cf] = (Xhi + Xlo) @ W1hi + b1 ----
    f32x4 acc[2][4];
#pragma unroll
    for (int cf = 0; cf < 4; ++cf) {
        float bv = b1[cf * 16 + lc];
        acc[0][cf] = (f32x4){bv, bv, bv, bv};
        acc[1][cf] = (f32x4){bv, bv, bv, bv};
    }
#pragma unroll
    for (int ks = 0; ks < 4; ++ks) {
        const float* ajp = Aj_row + ks * 32 + kg * 8;
        f32x4 aj0 = *(const f32x4*)ajp, aj1 = *(const f32x4*)(ajp + 4);
#pragma unroll
        for (int m = 0; m < 2; ++m) {
            const float* aip = (m ? Ai1 : Ai0) + ks * 32 + kg * 8;
            f32x4 ai0 = *(const f32x4*)aip, ai1 = *(const f32x4*)(aip + 4);
            float xs[8];
#pragma unroll
            for (int e = 0; e < 4; ++e) {
                xs[e]     = fmaxf(ai0[e] + aj0[e], 0.0f);
                xs[4 + e] = fmaxf(ai1[e] + aj1[e], 0.0f);
            }
            u32x4 hw, lw;
#pragma unroll
            for (int p = 0; p < 4; ++p) {
                uint32_t u0 = __builtin_bit_cast(uint32_t, xs[2 * p]);
                uint32_t u1 = __builtin_bit_cast(uint32_t, xs[2 * p + 1]);
                hw[p] = pack_hi2(u0, u1);
                float l0 = xs[2 * p]     - __builtin_bit_cast(float, u0 & 0xFFFF0000u);
                float l1 = xs[2 * p + 1] - __builtin_bit_cast(float, u1 & 0xFFFF0000u);
                lw[p] = pack_hi2(__builtin_bit_cast(uint32_t, l0),
                                 __builtin_bit_cast(uint32_t, l1));
            }
            s16x8 ahi = __builtin_bit_cast(s16x8, hw);
            s16x8 alo = __builtin_bit_cast(s16x8, lw);
#pragma unroll
            for (int cf = 0; cf < 4; ++cf) {
                int boff = (cf * 16 + lc) * 128 + (((ks * 4 + kg) ^ lc) << 3);
                s16x8 bhi = *(const s16x8*)(lw1h + boff);
                acc[m][cf] = __builtin_amdgcn_mfma_f32_16x16x32_bf16(ahi, bhi, acc[m][cf], 0, 0, 0);
                acc[m][cf] = __builtin_amdgcn_mfma_f32_16x16x32_bf16(alo, bhi, acc[m][cf], 0, 0, 0);
            }
        }
    }

    // ---- per-m: X2 -> layer3 -> X3 -> layer4 (all same-wave LDS) ----
#pragma unroll
    for (int m = 0; m < 2; ++m) {
        // X2 = relu(C1) bf16, swizzled [16][128B]
#pragma unroll
        for (int cf = 0; cf < 4; ++cf) {
            int g = cf * 2 + (lc >> 3);
#pragma unroll
            for (int r = 0; r < 4; ++r) {
                int row = kg * 4 + r;
                int off = row * 128 + ((g ^ (row & 7)) << 4) + (lc & 7) * 2;
                *(short*)(x2 + off) = (short)f2bf_rne(fmaxf(acc[m][cf][r], 0.0f));
            }
        }
        // layer 3
        f32x4 acc2[2];
#pragma unroll
        for (int cf = 0; cf < 2; ++cf) {
            float bv = b2[cf * 16 + lc];
            acc2[cf] = (f32x4){bv, bv, bv, bv};
        }
#pragma unroll
        for (int ks = 0; ks < 2; ++ks) {
            int aoff = lc * 128 + (((ks * 4 + kg) ^ (lc & 7)) << 4);
            s16x8 xa = *(const s16x8*)(x2 + aoff);
#pragma unroll
            for (int cf = 0; cf < 2; ++cf) {
                int b2off = (cf * 16 + lc) * 64 + (((ks * 4 + kg) ^ (lc & 7)) << 3);
                s16x8 bh = *(const s16x8*)(lw2h + b2off);
                s16x8 bl = *(const s16x8*)(lw2l + b2off);
                acc2[cf] = __builtin_amdgcn_mfma_f32_16x16x32_bf16(xa, bh, acc2[cf], 0, 0, 0);
                acc2[cf] = __builtin_amdgcn_mfma_f32_16x16x32_bf16(xa, bl, acc2[cf], 0, 0, 0);
            }
        }
        // X3 = relu(C2) bf16, swizzled [16][64B]
#pragma unroll
        for (int cf = 0; cf < 2; ++cf) {
            int g = cf * 2 + (lc >> 3);
#pragma unroll
            for (int r = 0; r < 4; ++r) {
                int row = kg * 4 + r;
                int off = row * 64 + ((g ^ (row & 3)) << 4) + (lc & 7) * 2;
                *(short*)(x3 + off) = (short)f2bf_rne(fmaxf(acc2[cf][r], 0.0f));
            }
        }
        // layer 4: one MFMA, every col of D = z
        int a4off = lc * 64 + ((kg ^ (lc & 3)) << 4);
        s16x8 x4 = *(const s16x8*)(x3 + a4off);
        f32x4 acc3 = (f32x4){b3v, b3v, b3v, b3v};
        acc3 = __builtin_amdgcn_mfma_f32_16x16x32_bf16(x4, bw3, acc3, 0, 0, 0);
        if (lc == 0) {
#pragma unroll
            for (int r = 0; r < 4; ++r)
                zb[(2 * w + m) * 17 + kg * 4 + r] = acc3[r];
        }
    }
    __syncthreads();

    // ---- coalesced stores + fused BCE/loss ----
    float num = 0.0f, den = 0.0f;
    if (t < 256) {                                   // primary 16x16, j >= i
        int r = t >> 4, c = t & 15;
        int i = iBase + r, j = jBase + c;
        if (j >= i) {
            float z = zb[r * 17 + c];
            size_t idx = ((size_t)n * SP + i) * SP + j;
            pred[idx] = z;
            float tg = heat[idx], mk = mask[idx], pm = pos[idx];
            float bce = fmaxf(z, 0.0f) - z * tg + __logf(1.0f + __expf(-fabsf(z)));
            num += bce * mk * pm;
            den += pm;
        }
    } else {                                         // mirror 16x16, J > I
        int tt = t - 256;
        int mr = tt >> 4, mc = tt & 15;
        int J = jBase + mr, I = iBase + mc;
        if (J > I) {
            float z = zb[mc * 17 + mr];
            size_t idx = ((size_t)n * SP + J) * SP + I;
            pred[idx] = z;
            float tg = heat[idx], mk = mask[idx], pm = pos[idx];
            float bce = fmaxf(z, 0.0f) - z * tg + __logf(1.0f + __expf(-fabsf(z)));
            num += bce * mk * pm;
            den += pm;
        }
    }
#pragma unroll
    for (int off = 32; off > 0; off >>= 1) {
        num += __shfl_down(num, off, 64);
        den += __shfl_down(den, off, 64);
    }
    if (l == 0) { rb[w] = num; rb[8 + w] = den; }
    __syncthreads();
    if (t == 0) {
        float sn = 0.0f, sd = 0.0f;
#pragma unroll
        for (int q = 0; q < 8; ++q) { sn += rb[q]; sd += rb[8 + q]; }
        atomicAdd(&accum[0], sn);
        atomicAdd(&accum[1], sd);
    }
}

__global__ void k_final(const float* __restrict__ accum, float* __restrict__ out)
{
    out[0] = accum[0] / accum[1];
}

extern "C" void kernel_launch(void* const* d_in, const int* in_sizes, int n_in,
                              void* d_out, int out_size, void* d_ws, size_t ws_size,
                              hipStream_t stream)
{
    const float* points = (const float*)d_in[0];
    const float* heat   = (const float*)d_in[1];
    const float* mask   = (const float*)d_in[2];
    const float* pos    = (const float*)d_in[3];
    const float* W0     = (const float*)d_in[4];
    const float* b0     = (const float*)d_in[5];
    const float* W1     = (const float*)d_in[6];
    const float* b1     = (const float*)d_in[7];
    const float* W2     = (const float*)d_in[8];
    const float* b2     = (const float*)d_in[9];
    const float* W3     = (const float*)d_in[10];
    const float* b3     = (const float*)d_in[11];

    float* pred = (float*)d_out;                        // (2,512,512)
    float* loss = pred + (size_t)N_ * SP * SP;          // scalar

    char* ws = (char*)d_ws;
    float* accum = (float*)ws;                          // [0]=num,[1]=den
    float* A     = (float*)(ws + 256);                  // 512 KiB
    short* W1Th  = (short*)(ws + 256 + 524288);         // wtab contiguous 24576B:
    short* W2Th  = (short*)(ws + 256 + 524288 + 16384); //   W1Th|W2Th|W2Tl
    short* W2Tl  = (short*)(ws + 256 + 524288 + 20480);

    hipMemsetAsync(d_ws, 0, 256, stream);
    k_precompA<<<256, 512, 0, stream>>>(points, W0, b0, W1, W2, A, W1Th, W2Th, W2Tl);
    k_main<<<dim3(528, 1, N_), 512, 0, stream>>>(
        A, W1Th, b1, b2, W3, b3, heat, mask, pos, pred, accum);
    k_final<<<1, 1, 0, stream>>>(accum, loss);
}

// Round 12
// 59.269 us; speedup vs baseline: 6.5570x; 1.0114x over previous
//
#include <hip/hip_runtime.h>
#include <stdint.h>

#define N_ 2
#define C_ 256
#define SP 512
#define H1 128
#define H2 64
#define H3 32

using f32x4 = __attribute__((ext_vector_type(4))) float;
using u32x4 = __attribute__((ext_vector_type(4))) unsigned int;
using s16x8 = __attribute__((ext_vector_type(8))) short;

__device__ __forceinline__ uint32_t f2bf_rne(float x) {
    uint32_t u = __builtin_bit_cast(uint32_t, x);
    return (u + 0x7FFFu + ((u >> 16) & 1u)) >> 16;
}
__device__ __forceinline__ float bf2f(uint32_t h) {
    return __builtin_bit_cast(float, h << 16);
}
__device__ __forceinline__ uint32_t pack_hi2(uint32_t u0, uint32_t u1) {
#if __has_builtin(__builtin_amdgcn_perm)
    return __builtin_amdgcn_perm(u1, u0, 0x07060302u);   // {u1.hi, u0.hi}
#else
    return (u0 >> 16) | (u1 & 0xFFFF0000u);
#endif
}

// A[row][k] = sum_c points[n][c][i]*W0[c][k] + 0.5*b0[k]; row = n*SP+i.
// c-split x4 teams; FUSED: also produces the swizzled bf16 W tables.
__global__ __launch_bounds__(512) void k_precompA(
    const float* __restrict__ points, const float* __restrict__ W0,
    const float* __restrict__ b0,
    const float* __restrict__ W1, const float* __restrict__ W2,
    float* __restrict__ A,
    short* __restrict__ W1Th, short* __restrict__ W2Th, short* __restrict__ W2Tl)
{
    int t = threadIdx.x;
    int k4 = t & 31;
    int team = t >> 5;
    int rloc = team & 3, cq = team >> 2;
    int row = blockIdx.x * 4 + rloc;
    int n = row >> 9, i = row & (SP - 1);
    const float* pb = points + (size_t)n * C_ * SP + i;
    f32x4 p0 = {0.f, 0.f, 0.f, 0.f}, p1 = {0.f, 0.f, 0.f, 0.f};
    int c0 = cq * 64;
#pragma unroll 8
    for (int c = c0; c < c0 + 64; c += 2) {
        float s0 = pb[(size_t)c * SP];
        float s1 = pb[(size_t)(c + 1) * SP];
        f32x4 w0v = *(const f32x4*)(W0 + c * H1 + k4 * 4);
        f32x4 w1v = *(const f32x4*)(W0 + (c + 1) * H1 + k4 * 4);
#pragma unroll
        for (int e = 0; e < 4; ++e) {
            p0[e] = fmaf(s0, w0v[e], p0[e]);
            p1[e] = fmaf(s1, w1v[e], p1[e]);
        }
    }
#pragma unroll
    for (int e = 0; e < 4; ++e) p0[e] += p1[e];
    __shared__ f32x4 part[16][32];
    part[team][k4] = p0;
    __syncthreads();
    int r2 = t >> 7, kk = t & 127;
    float s = 0.5f * b0[kk]
            + part[r2][kk >> 2][kk & 3] + part[r2 + 4][kk >> 2][kk & 3]
            + part[r2 + 8][kk >> 2][kk & 3] + part[r2 + 12][kk >> 2][kk & 3];
    A[(size_t)(blockIdx.x * 4 + r2) * H1 + kk] = s;

    // ---- fused W-prep ----
    int gid = blockIdx.x * 512 + t;
    int gstride = gridDim.x * 512;
    for (int idx = gid; idx < H2 * H1; idx += gstride) {      // W1 hi (rne) only
        int col = idx >> 7, k = idx & 127;
        int sidx = col * 128 + ((((k >> 3) ^ (col & 15)) << 3) | (k & 7));
        W1Th[sidx] = (short)f2bf_rne(W1[k * H2 + col]);
    }
    for (int idx = gid; idx < H3 * H2; idx += gstride) {      // W2 hi+lo
        int col = idx >> 6, k = idx & 63;
        float wv = W2[k * H3 + col];
        uint32_t h = f2bf_rne(wv);
        int sidx = col * 64 + ((((k >> 3) ^ (col & 7)) << 3) | (k & 7));
        W2Th[sidx] = (short)h;
        W2Tl[sidx] = (short)f2bf_rne(wv - bf2f(h));
    }
}

// Triangular grid u in [0,528): bi<=bj over 32 chunks of 16. Tile 16i x 16j,
// 8 waves, wave w owns i-rows {iBase+2w, iBase+2w+1}.
// R12: W tables read from GLOBAL (24KB -> L1-resident; R9's thrash was 40KB).
// Only the 16 A j-rows are LDS-staged (8KB, g^row swizzle, conflict-free);
// ai reads are kg-uniform broadcasts from L1. LDS 33.1KB -> 4 blocks/CU.
// Launch-bounds history: (512,8)->32reg spill; (512,4)->64reg spill; (512,3)
// gave VGPR 52 (JIT loads, stall-bound); (512,2) lets the compiler hoist.
__global__ __launch_bounds__(512, 2) void k_main(
    const float* __restrict__ A,
    const short* __restrict__ wtab,     // W1Th(16384B)|W2Th(4096B)|W2Tl(4096B)
    const float* __restrict__ b1, const float* __restrict__ b2,
    const float* __restrict__ W3, const float* __restrict__ b3,
    const float* __restrict__ heat, const float* __restrict__ mask,
    const float* __restrict__ pos,
    float* __restrict__ pred, float* __restrict__ accum)
{
    int u = blockIdx.x;
    int bi = (int)((65.0f - sqrtf(4225.0f - 8.0f * (float)u)) * 0.5f);
    int start = bi * (65 - bi) / 2;
    while (start > u) { --bi; start = bi * (65 - bi) / 2; }
    while (u - start >= 32 - bi) { ++bi; start = bi * (65 - bi) / 2; }
    int bj = bi + (u - start);
    int n = blockIdx.z;
    int iBase = bi * 16, jBase = bj * 16;

    // LDS: ajA 8192 | X2 8x2048 | X3 8x1024 | zb 16x17 f32 | red
    __shared__ __align__(16) char smem[8192 + 16384 + 8192 + 1088 + 64];
    int t = threadIdx.x;

    const short* lw1h = wtab;                        // global, L1-resident
    const short* lw2h = wtab + 8192;
    const short* lw2l = wtab + 10240;

    int l = t & 63, w = t >> 6;
    int lc = l & 15, kg = l >> 4;
    char* ajA = smem;                                // [16 rows][32 granules swz]
    char* x2 = smem + 8192 + w * 2048;               // [16][128B] swz
    char* x3 = smem + 8192 + 16384 + w * 1024;       // [16][64B] swz
    float* zb = (float*)(smem + 8192 + 16384 + 8192);
    float* rb = (float*)(smem + 8192 + 16384 + 8192 + 1088);

    const float* Abase = A + (size_t)n * SP * H1;

    // ---- stage A j-rows -> LDS (coalesced read, swizzled write) ----
    {
        int row = t >> 5;                            // 0..15
        int seg = t & 31;                            // 16B granule
        f32x4 v = *(const f32x4*)((const char*)(Abase + (size_t)(jBase + row) * H1) + seg * 16);
        *(f32x4*)(ajA + row * 512 + ((seg ^ row) << 4)) = v;
    }
    __syncthreads();

    const float* Ai0 = Abase + (size_t)(iBase + 2 * w) * H1;
    const float* Ai1 = Ai0 + H1;

    // W3 broadcast B-frag (bf16 rne) + b3
    s16x8 bw3;
    {
        f32x4 wa = *(const f32x4*)(W3 + kg * 8);
        f32x4 wb = *(const f32x4*)(W3 + kg * 8 + 4);
        u32x4 wp;
#pragma unroll
        for (int p = 0; p < 2; ++p) {
            wp[p]     = f2bf_rne(wa[2 * p]) | (f2bf_rne(wa[2 * p + 1]) << 16);
            wp[2 + p] = f2bf_rne(wb[2 * p]) | (f2bf_rne(wb[2 * p + 1]) << 16);
        }
        bw3 = __builtin_bit_cast(s16x8, wp);
    }
    float b3v = b3[0];

    // ---- layer 2: acc[m][cf] = (Xhi + Xlo) @ W1hi + b1 ----
    f32x4 acc[2][4];
#pragma unroll
    for (int cf = 0; cf < 4; ++cf) {
        float bv = b1[cf * 16 + lc];
        acc[0][cf] = (f32x4){bv, bv, bv, bv};
        acc[1][cf] = (f32x4){bv, bv, bv, bv};
    }
#pragma unroll
    for (int ks = 0; ks < 4; ++ks) {
        int g0 = ks * 8 + kg * 2;
        f32x4 aj0 = *(const f32x4*)(ajA + lc * 512 + ((g0 ^ lc) << 4));
        f32x4 aj1 = *(const f32x4*)(ajA + lc * 512 + (((g0 + 1) ^ lc) << 4));
#pragma unroll
        for (int m = 0; m < 2; ++m) {
            const float* aip = (m ? Ai1 : Ai0) + ks * 32 + kg * 8;   // 4-addr broadcast
            f32x4 ai0 = *(const f32x4*)aip, ai1 = *(const f32x4*)(aip + 4);
            float xs[8];
#pragma unroll
            for (int e = 0; e < 4; ++e) {
                xs[e]     = fmaxf(ai0[e] + aj0[e], 0.0f);
                xs[4 + e] = fmaxf(ai1[e] + aj1[e], 0.0f);
            }
            u32x4 hw, lw;
#pragma unroll
            for (int p = 0; p < 4; ++p) {
                uint32_t u0 = __builtin_bit_cast(uint32_t, xs[2 * p]);
                uint32_t u1 = __builtin_bit_cast(uint32_t, xs[2 * p + 1]);
                hw[p] = pack_hi2(u0, u1);
                float l0 = xs[2 * p]     - __builtin_bit_cast(float, u0 & 0xFFFF0000u);
                float l1 = xs[2 * p + 1] - __builtin_bit_cast(float, u1 & 0xFFFF0000u);
                lw[p] = pack_hi2(__builtin_bit_cast(uint32_t, l0),
                                 __builtin_bit_cast(uint32_t, l1));
            }
            s16x8 ahi = __builtin_bit_cast(s16x8, hw);
            s16x8 alo = __builtin_bit_cast(s16x8, lw);
#pragma unroll
            for (int cf = 0; cf < 4; ++cf) {
                int boff = (cf * 16 + lc) * 128 + (((ks * 4 + kg) ^ lc) << 3);
                s16x8 bhi = *(const s16x8*)(lw1h + boff);
                acc[m][cf] = __builtin_amdgcn_mfma_f32_16x16x32_bf16(ahi, bhi, acc[m][cf], 0, 0, 0);
                acc[m][cf] = __builtin_amdgcn_mfma_f32_16x16x32_bf16(alo, bhi, acc[m][cf], 0, 0, 0);
            }
        }
    }

    // ---- per-m: X2 -> layer3 -> X3 -> layer4 (same-wave LDS, no barrier) ----
#pragma unroll
    for (int m = 0; m < 2; ++m) {
#pragma unroll
        for (int cf = 0; cf < 4; ++cf) {
            int g = cf * 2 + (lc >> 3);
#pragma unroll
            for (int r = 0; r < 4; ++r) {
                int row = kg * 4 + r;
                int off = row * 128 + ((g ^ (row & 7)) << 4) + (lc & 7) * 2;
                *(short*)(x2 + off) = (short)f2bf_rne(fmaxf(acc[m][cf][r], 0.0f));
            }
        }
        f32x4 acc2[2];
#pragma unroll
        for (int cf = 0; cf < 2; ++cf) {
            float bv = b2[cf * 16 + lc];
            acc2[cf] = (f32x4){bv, bv, bv, bv};
        }
#pragma unroll
        for (int ks = 0; ks < 2; ++ks) {
            int aoff = lc * 128 + (((ks * 4 + kg) ^ (lc & 7)) << 4);
            s16x8 xa = *(const s16x8*)(x2 + aoff);
#pragma unroll
            for (int cf = 0; cf < 2; ++cf) {
                int b2off = (cf * 16 + lc) * 64 + (((ks * 4 + kg) ^ (lc & 7)) << 3);
                s16x8 bh = *(const s16x8*)(lw2h + b2off);
                s16x8 bl = *(const s16x8*)(lw2l + b2off);
                acc2[cf] = __builtin_amdgcn_mfma_f32_16x16x32_bf16(xa, bh, acc2[cf], 0, 0, 0);
                acc2[cf] = __builtin_amdgcn_mfma_f32_16x16x32_bf16(xa, bl, acc2[cf], 0, 0, 0);
            }
        }
#pragma unroll
        for (int cf = 0; cf < 2; ++cf) {
            int g = cf * 2 + (lc >> 3);
#pragma unroll
            for (int r = 0; r < 4; ++r) {
                int row = kg * 4 + r;
                int off = row * 64 + ((g ^ (row & 3)) << 4) + (lc & 7) * 2;
                *(short*)(x3 + off) = (short)f2bf_rne(fmaxf(acc2[cf][r], 0.0f));
            }
        }
        int a4off = lc * 64 + ((kg ^ (lc & 3)) << 4);
        s16x8 x4 = *(const s16x8*)(x3 + a4off);
        f32x4 acc3 = (f32x4){b3v, b3v, b3v, b3v};
        acc3 = __builtin_amdgcn_mfma_f32_16x16x32_bf16(x4, bw3, acc3, 0, 0, 0);
        if (lc == 0) {
#pragma unroll
            for (int r = 0; r < 4; ++r)
                zb[(2 * w + m) * 17 + kg * 4 + r] = acc3[r];
        }
    }
    __syncthreads();

    // ---- coalesced stores + fused BCE/loss ----
    float num = 0.0f, den = 0.0f;
    if (t < 256) {                                   // primary 16x16, j >= i
        int r = t >> 4, c = t & 15;
        int i = iBase + r, j = jBase + c;
        if (j >= i) {
            float z = zb[r * 17 + c];
            size_t idx = ((size_t)n * SP + i) * SP + j;
            pred[idx] = z;
            float tg = heat[idx], mk = mask[idx], pm = pos[idx];
            float bce = fmaxf(z, 0.0f) - z * tg + __logf(1.0f + __expf(-fabsf(z)));
            num += bce * mk * pm;
            den += pm;
        }
    } else {                                         // mirror 16x16, J > I
        int tt = t - 256;
        int mr = tt >> 4, mc = tt & 15;
        int J = jBase + mr, I = iBase + mc;
        if (J > I) {
            float z = zb[mc * 17 + mr];
            size_t idx = ((size_t)n * SP + J) * SP + I;
            pred[idx] = z;
            float tg = heat[idx], mk = mask[idx], pm = pos[idx];
            float bce = fmaxf(z, 0.0f) - z * tg + __logf(1.0f + __expf(-fabsf(z)));
            num += bce * mk * pm;
            den += pm;
        }
    }
#pragma unroll
    for (int off = 32; off > 0; off >>= 1) {
        num += __shfl_down(num, off, 64);
        den += __shfl_down(den, off, 64);
    }
    if (l == 0) { rb[w] = num; rb[8 + w] = den; }
    __syncthreads();
    if (t == 0) {
        float sn = 0.0f, sd = 0.0f;
#pragma unroll
        for (int q = 0; q < 8; ++q) { sn += rb[q]; sd += rb[8 + q]; }
        atomicAdd(&accum[0], sn);
        atomicAdd(&accum[1], sd);
    }
}

__global__ void k_final(const float* __restrict__ accum, float* __restrict__ out)
{
    out[0] = accum[0] / accum[1];
}

extern "C" void kernel_launch(void* const* d_in, const int* in_sizes, int n_in,
                              void* d_out, int out_size, void* d_ws, size_t ws_size,
                              hipStream_t stream)
{
    const float* points = (const float*)d_in[0];
    const float* heat   = (const float*)d_in[1];
    const float* mask   = (const float*)d_in[2];
    const float* pos    = (const float*)d_in[3];
    const float* W0     = (const float*)d_in[4];
    const float* b0     = (const float*)d_in[5];
    const float* W1     = (const float*)d_in[6];
    const float* b1     = (const float*)d_in[7];
    const float* W2     = (const float*)d_in[8];
    const float* b2     = (const float*)d_in[9];
    const float* W3     = (const float*)d_in[10];
    const float* b3     = (const float*)d_in[11];

    float* pred = (float*)d_out;                        // (2,512,512)
    float* loss = pred + (size_t)N_ * SP * SP;          // scalar

    char* ws = (char*)d_ws;
    float* accum = (float*)ws;                          // [0]=num,[1]=den
    float* A     = (float*)(ws + 256);                  // 512 KiB
    short* W1Th  = (short*)(ws + 256 + 524288);         // wtab contiguous 24576B:
    short* W2Th  = (short*)(ws + 256 + 524288 + 16384); //   W1Th|W2Th|W2Tl
    short* W2Tl  = (short*)(ws + 256 + 524288 + 20480);

    hipMemsetAsync(d_ws, 0, 256, stream);
    k_precompA<<<256, 512, 0, stream>>>(points, W0, b0, W1, W2, A, W1Th, W2Th, W2Tl);
    k_main<<<dim3(528, 1, N_), 512, 0, stream>>>(
        A, W1Th, b1, b2, W3, b3, heat, mask, pos, pred, accum);
    k_final<<<1, 1, 0, stream>>>(accum, loss);
}